// Round 10
// baseline (2210.015 us; speedup 1.0000x reference)
//
#include <hip/hip_runtime.h>
#include <math.h>

typedef __attribute__((ext_vector_type(8))) short bf16x8;
typedef __attribute__((ext_vector_type(4))) float floatx4;
typedef __attribute__((ext_vector_type(2))) float floatx2;

#define ROWP 224          // padded row length (elements) for h/agg bf16 buffers
#define NT 14             // 14 x 16 = 224 output cols (200 real + pad)
#define KS 7              // 7 x 32 = 224 K (200 real + pad)
#define PACK_ELEMS (NT*KS*64*8)   // elements per packed weight matrix (layers 2..5)
#define PACK1_ELEMS (NT*64*8)     // layer-1 packed weight (K=32)
#define BSHIFT 6          // 64 nodes per CSR bucket
#define EPB 4096          // edges per binning block
#define MAXBUCK 1600      // LDS capacity for bucket arrays (>= nbuck=1563)

__device__ __forceinline__ unsigned short f2bf(float f){
    union { float f; unsigned u; } v; v.f = f;
    unsigned r = v.u + 0x7FFF + ((v.u >> 16) & 1);
    return (unsigned short)(r >> 16);
}
__device__ __forceinline__ float bf2f(unsigned short u){
    union { unsigned u; float f; } v; v.u = ((unsigned)u) << 16;
    return v.f;
}

// ============================ binned CSR build (no hot global atomics) ============================

__global__ __launch_bounds__(256) void k_bin_hist(
    const int* __restrict__ dst, int* __restrict__ hist, int E, int nbuck)
{
    __shared__ int lh[MAXBUCK];
    for (int i = threadIdx.x; i < nbuck; i += 256) lh[i] = 0;
    __syncthreads();
    int base = blockIdx.x * EPB;
    #pragma unroll
    for (int k = 0; k < EPB / 256; ++k){
        int e = base + k * 256 + threadIdx.x;
        if (e < E) atomicAdd(&lh[dst[e] >> BSHIFT], 1);
    }
    __syncthreads();
    for (int i = threadIdx.x; i < nbuck; i += 256)
        hist[(size_t)blockIdx.x * nbuck + i] = lh[i];
}

__global__ __launch_bounds__(256) void k_col_scan(
    int* __restrict__ hist, int* __restrict__ T, int nblk, int nbuck)
{
    __shared__ int part[4][64];
    int w = threadIdx.x >> 6, l = threadIdx.x & 63;
    int b = blockIdx.x * 64 + l;
    int chunk = (nblk + 3) >> 2;
    int j0 = w * chunk, j1 = j0 + chunk; if (j1 > nblk) j1 = nblk;
    int s = 0;
    if (b < nbuck)
        for (int j = j0; j < j1; ++j) s += hist[(size_t)j * nbuck + b];
    part[w][l] = s;
    __syncthreads();
    if (b < nbuck){
        int run = 0;
        for (int w2 = 0; w2 < w; ++w2) run += part[w2][l];
        for (int j = j0; j < j1; ++j){
            int v = hist[(size_t)j * nbuck + b];
            hist[(size_t)j * nbuck + b] = run;
            run += v;
        }
        if (w == 3) T[b] = part[0][l] + part[1][l] + part[2][l] + part[3][l];
    }
}

__global__ __launch_bounds__(256) void k_scan_t(
    const int* __restrict__ T, int* __restrict__ tbase, int nbuck)
{
    __shared__ int ts[256];
    int t = threadIdx.x;
    int v[8]; int s = 0;
    int base = t * 8;
    #pragma unroll
    for (int k = 0; k < 8; ++k){
        int idx = base + k;
        v[k] = (idx < nbuck) ? T[idx] : 0;
        s += v[k];
    }
    ts[t] = s; __syncthreads();
    #pragma unroll
    for (int off = 1; off < 256; off <<= 1){
        int p = (t >= off) ? ts[t - off] : 0;
        __syncthreads();
        ts[t] += p;
        __syncthreads();
    }
    int run = ts[t] - s;
    #pragma unroll
    for (int k = 0; k < 8; ++k){
        int idx = base + k;
        if (idx < nbuck) tbase[idx] = run;
        run += v[k];
    }
    if (t == 255) tbase[nbuck] = ts[255];
}

__global__ __launch_bounds__(256) void k_bin_scatter(
    const int* __restrict__ src, const int* __restrict__ dst,
    const int* __restrict__ off, const int* __restrict__ tbase,
    int2* __restrict__ pairs, int E, int nbuck)
{
    __shared__ int lbase[MAXBUCK];
    __shared__ int lc[MAXBUCK];
    for (int i = threadIdx.x; i < nbuck; i += 256){
        lbase[i] = off[(size_t)blockIdx.x * nbuck + i] + tbase[i];
        lc[i] = 0;
    }
    __syncthreads();
    int base = blockIdx.x * EPB;
    #pragma unroll
    for (int k = 0; k < EPB / 256; ++k){
        int e = base + k * 256 + threadIdx.x;
        if (e < E){
            int d = dst[e];
            int b = d >> BSHIFT;
            int r = atomicAdd(&lc[b], 1);
            pairs[lbase[b] + r] = make_int2(src[e], d);
        }
    }
}

__global__ __launch_bounds__(256) void k_bucket_deg(
    const int2* __restrict__ pairs, const int* __restrict__ tbase,
    int* __restrict__ deg, int N)
{
    __shared__ int ld[64];
    int b = blockIdx.x;
    if (threadIdx.x < 64) ld[threadIdx.x] = 0;
    __syncthreads();
    int pb = tbase[b], pe = tbase[b + 1];
    for (int e = pb + threadIdx.x; e < pe; e += 256)
        atomicAdd(&ld[pairs[e].y & 63], 1);
    __syncthreads();
    if (threadIdx.x < 64){
        int node = (b << BSHIFT) + threadIdx.x;
        if (node < N) deg[node] = ld[threadIdx.x];
    }
}

__global__ __launch_bounds__(256) void k_place(
    const int2* __restrict__ pairs, const int* __restrict__ tbase,
    const int* __restrict__ row_ptr, int* __restrict__ srcs, int N)
{
    __shared__ int lrp[64];
    __shared__ int lcur[64];
    int b = blockIdx.x;
    if (threadIdx.x < 64){
        int node = (b << BSHIFT) + threadIdx.x;
        lrp[threadIdx.x] = (node < N) ? row_ptr[node] : 0;
        lcur[threadIdx.x] = 0;
    }
    __syncthreads();
    int pb = tbase[b], pe = tbase[b + 1];
    for (int e = pb + threadIdx.x; e < pe; e += 256){
        int2 pr = pairs[e];
        int li = pr.y & 63;
        int r = atomicAdd(&lcur[li], 1);
        srcs[lrp[li] + r] = pr.x;
    }
}

// ============================ row_ptr scan (over deg) ============================

__global__ void k_scan_sums(const int* __restrict__ deg, int* __restrict__ csum, int N){
    __shared__ int sd[256];
    int base = blockIdx.x * 1024;
    int s = 0;
    for (int i = threadIdx.x; i < 1024; i += 256){
        int idx = base + i;
        s += (idx < N) ? deg[idx] : 0;
    }
    sd[threadIdx.x] = s; __syncthreads();
    for (int off = 128; off > 0; off >>= 1){
        if (threadIdx.x < off) sd[threadIdx.x] += sd[threadIdx.x + off];
        __syncthreads();
    }
    if (threadIdx.x == 0) csum[blockIdx.x] = sd[0];
}

__global__ void k_scan_top(int* __restrict__ csum, int n){
    if (blockIdx.x == 0 && threadIdx.x == 0){
        int run = 0;
        for (int i = 0; i < n; ++i){ int v = csum[i]; csum[i] = run; run += v; }
    }
}

__global__ void k_scan_apply(const int* __restrict__ deg, const int* __restrict__ csum,
                             int* __restrict__ row_ptr, int N, int E){
    __shared__ int ts[256];
    int base = blockIdx.x * 1024 + threadIdx.x * 4;
    int v[4]; int s = 0;
    #pragma unroll
    for (int j = 0; j < 4; ++j){
        int idx = base + j;
        v[j] = (idx < N) ? deg[idx] : 0;
        s += v[j];
    }
    ts[threadIdx.x] = s; __syncthreads();
    #pragma unroll
    for (int off = 1; off < 256; off <<= 1){
        int t = (threadIdx.x >= off) ? ts[threadIdx.x - off] : 0;
        __syncthreads();
        ts[threadIdx.x] += t;
        __syncthreads();
    }
    int excl = ts[threadIdx.x] - s + csum[blockIdx.x];
    #pragma unroll
    for (int j = 0; j < 4; ++j){
        int idx = base + j;
        if (idx < N) row_ptr[idx] = excl;
        excl += v[j];
    }
    if (blockIdx.x == 0 && threadIdx.x == 0) row_ptr[N] = E;
}

__global__ void k_inv_deg(const int* __restrict__ deg, float* __restrict__ inv_deg, int N){
    int i = blockIdx.x * blockDim.x + threadIdx.x;
    if (i < N) inv_deg[i] = 1.0f / fmaxf((float)deg[i], 1.0f);
}

// ============================ graph segment starts ============================

__global__ void k_gstart_init(int* __restrict__ gstart, int N, int NG){
    int g = blockIdx.x * blockDim.x + threadIdx.x;
    if (g <= NG) gstart[g] = N;
}

__global__ void k_gstart_mark(const int* __restrict__ batch, int* __restrict__ gstart, int N){
    int i = blockIdx.x * blockDim.x + threadIdx.x;
    if (i < N){
        int b = batch[i];
        if (i == 0 || batch[i-1] != b) atomicMin(&gstart[b], i);
    }
}

__global__ void k_gstart_fix(int* __restrict__ gstart, int N, int NG){
    if (blockIdx.x == 0 && threadIdx.x == 0){
        for (int g = NG - 1; g >= 0; --g)
            if (gstart[g] == N) gstart[g] = gstart[g+1];
    }
}

// ============================ weight / bias / x packing ============================

__global__ void k_pack_w(const float* W0, const float* W1, const float* W2, const float* W3,
                         const float* W4, const float* W5, const float* W6, const float* W7,
                         unsigned short* __restrict__ out){
    const float* Ws[8] = {W0,W1,W2,W3,W4,W5,W6,W7};
    const float* W = Ws[blockIdx.z];
    int lane = threadIdx.x;
    int n  = blockIdx.x * 16 + (lane & 15);
    int k0 = blockIdx.y * 32 + (lane >> 4) * 8;
    unsigned short v[8];
    #pragma unroll
    for (int j = 0; j < 8; ++j){
        int k = k0 + j;
        float f = (n < 200 && k < 200) ? W[n * 200 + k] : 0.f;
        v[j] = f2bf(f);
    }
    uint4 u;
    u.x = (unsigned)v[0] | ((unsigned)v[1] << 16);
    u.y = (unsigned)v[2] | ((unsigned)v[3] << 16);
    u.z = (unsigned)v[4] | ((unsigned)v[5] << 16);
    u.w = (unsigned)v[6] | ((unsigned)v[7] << 16);
    size_t off = ((((size_t)blockIdx.z * NT + blockIdx.x) * KS + blockIdx.y) * 64 + lane) * 8;
    *reinterpret_cast<uint4*>(out + off) = u;
}

// layer-1: pack concatenated [Wl1 (K 0..10) | pad | Wr1 (K 16..26) | pad] 224x32
__global__ void k_pack_w1(const float* __restrict__ Wl, const float* __restrict__ Wr,
                          unsigned short* __restrict__ out){
    int lane = threadIdx.x;
    int n  = blockIdx.x * 16 + (lane & 15);
    int k0 = (lane >> 4) * 8;
    unsigned short v[8];
    #pragma unroll
    for (int j = 0; j < 8; ++j){
        int k = k0 + j;
        float f = 0.f;
        if (n < 200){
            if (k < 11)                 f = Wl[n * 11 + k];
            else if (k >= 16 && k < 27) f = Wr[n * 11 + (k - 16)];
        }
        v[j] = f2bf(f);
    }
    uint4 u;
    u.x = (unsigned)v[0] | ((unsigned)v[1] << 16);
    u.y = (unsigned)v[2] | ((unsigned)v[3] << 16);
    u.z = (unsigned)v[4] | ((unsigned)v[5] << 16);
    u.w = (unsigned)v[6] | ((unsigned)v[7] << 16);
    size_t off = ((size_t)blockIdx.x * 64 + lane) * 8;
    *reinterpret_cast<uint4*>(out + off) = u;
}

__global__ void k_pack_b(const float* b0, const float* b1, const float* b2, const float* b3,
                         const float* b4, float* __restrict__ out){
    const float* bs[5] = {b0,b1,b2,b3,b4};
    int l = blockIdx.x, c = threadIdx.x;
    if (c < ROWP) out[l * ROWP + c] = (c < 200) ? bs[l][c] : 0.f;
}

__global__ void k_pack_x(const float* __restrict__ x, unsigned short* __restrict__ xp,
                         unsigned short* __restrict__ xa, int N){
    int i = blockIdx.x * blockDim.x + threadIdx.x;
    int node = i >> 4, c = i & 15;
    if (node < N){
        unsigned short v = (c < 11) ? f2bf(x[(size_t)node * 11 + c]) : 0;
        xp[i] = v;
        xa[(size_t)node * 32 + 16 + c] = v;
    }
}

// ============================ aggregation ============================

// K=11 edge-parallel: half-wave (32 lanes) per node, one edge per lane.
__global__ __launch_bounds__(256) void k_agg11(
    const unsigned short* __restrict__ xp, const int* __restrict__ row_ptr,
    const int* __restrict__ srcs, const float* __restrict__ inv_deg,
    unsigned short* __restrict__ xa, int N)
{
    int half = threadIdx.x >> 5;              // 0..7
    int node = blockIdx.x * 8 + half;
    int l = threadIdx.x & 31;
    if (node >= N) return;
    int beg = row_ptr[node], end = row_ptr[node + 1];

    float acc[12];
    #pragma unroll
    for (int i = 0; i < 12; ++i) acc[i] = 0.f;

    const uint4* x4 = reinterpret_cast<const uint4*>(xp);
    const uint2* x2 = reinterpret_cast<const uint2*>(xp);
    for (int e = beg + l; e < end; e += 32){
        int sn = srcs[e];
        uint4 a = x4[(size_t)sn * 2];
        uint2 b = x2[(size_t)sn * 4 + 2];
        union { unsigned u; float f; } c;
        c.u = a.x << 16;         acc[0] += c.f;
        c.u = a.x & 0xffff0000u; acc[1] += c.f;
        c.u = a.y << 16;         acc[2] += c.f;
        c.u = a.y & 0xffff0000u; acc[3] += c.f;
        c.u = a.z << 16;         acc[4] += c.f;
        c.u = a.z & 0xffff0000u; acc[5] += c.f;
        c.u = a.w << 16;         acc[6] += c.f;
        c.u = a.w & 0xffff0000u; acc[7] += c.f;
        c.u = b.x << 16;         acc[8] += c.f;
        c.u = b.x & 0xffff0000u; acc[9] += c.f;
        c.u = b.y << 16;         acc[10] += c.f;
        c.u = b.y & 0xffff0000u; acc[11] += c.f;
    }

    #pragma unroll
    for (int i = 0; i < 11; ++i){
        acc[i] += __shfl_xor(acc[i], 1, 64);
        acc[i] += __shfl_xor(acc[i], 2, 64);
        acc[i] += __shfl_xor(acc[i], 4, 64);
        acc[i] += __shfl_xor(acc[i], 8, 64);
        acc[i] += __shfl_xor(acc[i], 16, 64);
    }

    if (l == 0){
        float id = inv_deg[node];
        unsigned short b[12];
        #pragma unroll
        for (int i = 0; i < 11; ++i) b[i] = f2bf(acc[i] * id);
        b[11] = 0;
        uint4 o0, o1;
        o0.x = (unsigned)b[0] | ((unsigned)b[1] << 16);
        o0.y = (unsigned)b[2] | ((unsigned)b[3] << 16);
        o0.z = (unsigned)b[4] | ((unsigned)b[5] << 16);
        o0.w = (unsigned)b[6] | ((unsigned)b[7] << 16);
        o1.x = (unsigned)b[8] | ((unsigned)b[9] << 16);
        o1.y = (unsigned)b[10] | ((unsigned)b[11] << 16);
        o1.z = 0u; o1.w = 0u;
        uint4* dst4 = reinterpret_cast<uint4*>(xa + (size_t)node * 32);
        dst4[0] = o0;
        dst4[1] = o1;
    }
}

// fp8 gather-aggregate (layers 2..5). One wave per dst node.
__device__ __forceinline__ void accum_fp8(float* acc, uint4 u){
    floatx2 f;
    f = __builtin_amdgcn_cvt_pk_f32_fp8((int)u.x, false); acc[0] += f[0];  acc[1] += f[1];
    f = __builtin_amdgcn_cvt_pk_f32_fp8((int)u.x, true ); acc[2] += f[0];  acc[3] += f[1];
    f = __builtin_amdgcn_cvt_pk_f32_fp8((int)u.y, false); acc[4] += f[0];  acc[5] += f[1];
    f = __builtin_amdgcn_cvt_pk_f32_fp8((int)u.y, true ); acc[6] += f[0];  acc[7] += f[1];
    f = __builtin_amdgcn_cvt_pk_f32_fp8((int)u.z, false); acc[8] += f[0];  acc[9] += f[1];
    f = __builtin_amdgcn_cvt_pk_f32_fp8((int)u.z, true ); acc[10] += f[0]; acc[11] += f[1];
    f = __builtin_amdgcn_cvt_pk_f32_fp8((int)u.w, false); acc[12] += f[0]; acc[13] += f[1];
    f = __builtin_amdgcn_cvt_pk_f32_fp8((int)u.w, true ); acc[14] += f[0]; acc[15] += f[1];
}

__global__ __launch_bounds__(256) void k_agg200(
    const unsigned char* __restrict__ h8, const int* __restrict__ row_ptr,
    const int* __restrict__ srcs, const float* __restrict__ inv_deg,
    unsigned short* __restrict__ agg, int N)
{
    int node = blockIdx.x * 4 + (threadIdx.x >> 6);
    int lane = threadIdx.x & 63;
    if (node >= N) return;
    int g = lane >> 4;    // group 0..3
    int l = lane & 15;    // lane-in-group; active if l < 14
    int beg = row_ptr[node], end = row_ptr[node + 1];

    float acc[16];
    #pragma unroll
    for (int i = 0; i < 16; ++i) acc[i] = 0.f;

    if (l < 14){
        const uint4* h4 = reinterpret_cast<const uint4*>(h8);
        int e = beg + g;
        for (; e + 4 < end; e += 8){
            int sa = srcs[e];
            int sb = srcs[e + 4];
            uint4 ua = h4[(size_t)sa * 14 + l];
            uint4 ub = h4[(size_t)sb * 14 + l];
            accum_fp8(acc, ua);
            accum_fp8(acc, ub);
        }
        if (e < end){
            int sa = srcs[e];
            uint4 ua = h4[(size_t)sa * 14 + l];
            accum_fp8(acc, ua);
        }
    }

    #pragma unroll
    for (int i = 0; i < 16; ++i){
        acc[i] += __shfl_xor(acc[i], 32, 64);
        acc[i] += __shfl_xor(acc[i], 16, 64);
    }

    if (g == 0 && l < 14){
        float id = inv_deg[node];
        unsigned d[8];
        #pragma unroll
        for (int i = 0; i < 8; ++i){
            d[i] = (unsigned)f2bf(acc[2*i] * id) | ((unsigned)f2bf(acc[2*i+1] * id) << 16);
        }
        uint4* a4 = reinterpret_cast<uint4*>(agg);
        size_t base = (size_t)node * 28 + (size_t)l * 2;
        uint4 o0; o0.x = d[0]; o0.y = d[1]; o0.z = d[2]; o0.w = d[3];
        uint4 o1; o1.x = d[4]; o1.y = d[5]; o1.z = d[6]; o1.w = d[7];
        a4[base] = o0;
        a4[base + 1] = o1;
    }
}

// ============================ layer-1 MFMA (K=32: [agg11 | x11]) ============================

__global__ __launch_bounds__(256) void k_layer1_mfma(
    const unsigned short* __restrict__ xa, const unsigned short* __restrict__ W1p,
    const float* __restrict__ biasp, unsigned short* __restrict__ outp, int M)
{
    const int wave = threadIdx.x >> 6;
    const int lane = threadIdx.x & 63;
    const int n = lane & 15;
    const int q = lane >> 4;
    int row = blockIdx.x * 64 + wave * 16 + n;
    int rowc = row < M ? row : (M - 1);

    bf16x8 a = *reinterpret_cast<const bf16x8*>(xa + (size_t)rowc * 32 + q * 8);

    floatx4 acc[NT];
    #pragma unroll
    for (int nt = 0; nt < NT; ++nt){
        bf16x8 b = *reinterpret_cast<const bf16x8*>(W1p + ((size_t)nt * 64 + lane) * 8);
        acc[nt] = __builtin_amdgcn_mfma_f32_16x16x32_bf16(a, b, (floatx4){0.f,0.f,0.f,0.f}, 0, 0, 0);
    }

    int r0 = blockIdx.x * 64 + wave * 16 + q * 4;
    #pragma unroll
    for (int nt = 0; nt < NT; ++nt){
        float bsv = biasp[nt * 16 + n];
        #pragma unroll
        for (int r = 0; r < 4; ++r){
            int rr = r0 + r;
            if (rr < M){
                float v = fmaxf(acc[nt][r] + bsv, 0.f);
                outp[(size_t)rr * ROWP + nt * 16 + n] = f2bf(v);
            }
        }
    }
}

// ============================ MFMA SAGE GEMM (layers 2..5) ============================
// 32 rows per wave (two 16-row tiles): each B-fragment global load feeds TWO
// MFMAs -> halves B L2-traffic vs round-7 (1.22 GB -> 0.61 GB/dispatch).
// No LDS, no barriers, no launch_bounds min-wave pin (round-9's (256,3) caused
// accumulator spill to scratch: WRITE 85 MB vs 45 logical, occupancy 0.9%).
__global__ __launch_bounds__(256) void k_sage_mfma(
    const unsigned short* __restrict__ Aagg, const unsigned short* __restrict__ Ah,
    const unsigned short* __restrict__ Wlp, const unsigned short* __restrict__ Wrp,
    const float* __restrict__ biasp, unsigned short* __restrict__ outp, int M)
{
    const int wave = threadIdx.x >> 6;
    const int lane = threadIdx.x & 63;
    const int n = lane & 15;
    const int q = lane >> 4;
    const int base = blockIdx.x * 128 + wave * 32;
    int row0 = base + n;
    int row1 = base + 16 + n;
    int r0c = row0 < M ? row0 : (M - 1);
    int r1c = row1 < M ? row1 : (M - 1);

    floatx4 acc0[NT], acc1[NT];
    #pragma unroll
    for (int nt = 0; nt < NT; ++nt){
        acc0[nt] = (floatx4){0.f, 0.f, 0.f, 0.f};
        acc1[nt] = (floatx4){0.f, 0.f, 0.f, 0.f};
    }

    #pragma unroll
    for (int phase = 0; phase < 2; ++phase){
        const unsigned short* A = phase ? Ah : Aagg;
        const unsigned short* Wp = phase ? Wrp : Wlp;
        const unsigned short* arow0 = A + (size_t)r0c * ROWP + q * 8;
        const unsigned short* arow1 = A + (size_t)r1c * ROWP + q * 8;
        #pragma unroll
        for (int ks = 0; ks < KS; ++ks){
            bf16x8 a0 = *reinterpret_cast<const bf16x8*>(arow0 + ks * 32);
            bf16x8 a1 = *reinterpret_cast<const bf16x8*>(arow1 + ks * 32);
            #pragma unroll
            for (int nt = 0; nt < NT; ++nt){
                bf16x8 b = *reinterpret_cast<const bf16x8*>(Wp + ((size_t)(nt * KS + ks) * 64 + lane) * 8);
                acc0[nt] = __builtin_amdgcn_mfma_f32_16x16x32_bf16(a0, b, acc0[nt], 0, 0, 0);
                acc1[nt] = __builtin_amdgcn_mfma_f32_16x16x32_bf16(a1, b, acc1[nt], 0, 0, 0);
            }
        }
    }

    // epilogue: C/D layout col=lane&15, row=(lane>>4)*4+reg; two 16-row tiles
    int e0 = base + q * 4;
    int e1 = base + 16 + q * 4;
    #pragma unroll
    for (int nt = 0; nt < NT; ++nt){
        float bsv = biasp[nt * 16 + n];
        #pragma unroll
        for (int r = 0; r < 4; ++r){
            int rr = e0 + r;
            if (rr < M){
                float v = fmaxf(acc0[nt][r] + bsv, 0.f);
                outp[(size_t)rr * ROWP + nt * 16 + n] = f2bf(v);
            }
            int rr1 = e1 + r;
            if (rr1 < M){
                float v = fmaxf(acc1[nt][r] + bsv, 0.f);
                outp[(size_t)rr1 * ROWP + nt * 16 + n] = f2bf(v);
            }
        }
    }
}

// ============================ pooling + fp8 shadow write ============================

__global__ __launch_bounds__(256) void k_pool(
    const unsigned short* __restrict__ h, const int* __restrict__ gstart,
    float* __restrict__ gsum, int col_off, unsigned char* __restrict__ h8)
{
    int g = blockIdx.x;
    int beg = gstart[g], end = gstart[g+1];
    int len = end - beg;
    if (len <= 0) return;
    int sub = threadIdx.x >> 6;                 // 0..3
    int t   = threadIdx.x & 63;                 // lane
    if (t >= 56) return;
    int pidx = blockIdx.y * 4 + sub;            // 0..31
    int chunk = (len + 31) >> 5;
    int rb = beg + pidx * chunk;
    int re = rb + chunk; if (re > end) re = end;
    if (rb >= re) return;
    int c0 = t * 4;

    float s0 = 0.f, s1 = 0.f, s2 = 0.f, s3 = 0.f;
    for (int r = rb; r < re; ++r){
        uint2 u = *reinterpret_cast<const uint2*>(h + (size_t)r * ROWP + c0);
        union { unsigned u; float f; } c;
        float v0, v1, v2, v3;
        c.u = u.x << 16;         v0 = c.f;
        c.u = u.x & 0xffff0000u; v1 = c.f;
        c.u = u.y << 16;         v2 = c.f;
        c.u = u.y & 0xffff0000u; v3 = c.f;
        s0 += v0; s1 += v1; s2 += v2; s3 += v3;
        int pk = __builtin_amdgcn_cvt_pk_fp8_f32(v0, v1, 0, false);
        pk = __builtin_amdgcn_cvt_pk_fp8_f32(v2, v3, pk, true);
        *reinterpret_cast<unsigned*>(h8 + (size_t)r * ROWP + c0) = (unsigned)pk;
    }
    if (c0 < 200){
        float* gs = &gsum[(size_t)g * 1000 + col_off + c0];
        atomicAdd(gs + 0, s0);
        atomicAdd(gs + 1, s1);
        atomicAdd(gs + 2, s2);
        atomicAdd(gs + 3, s3);
    }
}

__global__ __launch_bounds__(256) void k_pool_finalize(
    float* __restrict__ gsum, const int* __restrict__ gstart, int NG)
{
    int g = blockIdx.x;
    int cnt = gstart[g+1] - gstart[g];
    float inv = 1.0f / fmaxf((float)cnt, 1.0f);
    for (int i = threadIdx.x; i < 1000; i += 256)
        gsum[(size_t)g * 1000 + i] *= inv;
}

// ============================ MLP head (fp32) ============================

__global__ __launch_bounds__(256) void k_mlp(
    const float* __restrict__ in, const float* __restrict__ W,
    const float* __restrict__ b, float* __restrict__ outp, int Fin, int Fout)
{
    __shared__ __align__(16) float row[1000];
    int g = blockIdx.x;
    for (int i = threadIdx.x; i < Fin; i += 256) row[i] = in[(size_t)g * Fin + i];
    __syncthreads();
    int f4 = Fin >> 2;
    for (int c = threadIdx.x; c < Fout; c += 256){
        const float4* w4 = reinterpret_cast<const float4*>(W + (size_t)c * Fin);
        const float4* r4 = reinterpret_cast<const float4*>(row);
        float s = b[c];
        for (int k = 0; k < f4; ++k){
            float4 wv = w4[k]; float4 rv = r4[k];
            s = fmaf(wv.x, rv.x, s);
            s = fmaf(wv.y, rv.y, s);
            s = fmaf(wv.z, rv.z, s);
            s = fmaf(wv.w, rv.w, s);
        }
        outp[(size_t)g * Fout + c] = s;
    }
}

__global__ void k_mlp3(const float* __restrict__ in, const float* __restrict__ W,
                       const float* __restrict__ b, float* __restrict__ outp, int NG)
{
    int g = blockIdx.x * blockDim.x + threadIdx.x;
    if (g < NG){
        float s = b[0];
        const float* r = in + (size_t)g * 250;
        for (int k = 0; k < 250; ++k) s = fmaf(r[k], W[k], s);
        outp[g] = 1.0f / (1.0f + expf(-s));
    }
}

// ============================ launch ============================

extern "C" void kernel_launch(void* const* d_in, const int* in_sizes, int n_in,
                              void* d_out, int out_size, void* d_ws, size_t ws_size,
                              hipStream_t stream)
{
    const float* x    = (const float*)d_in[0];
    const int*   ei   = (const int*)d_in[1];
    const int*   batch= (const int*)d_in[2];
    const float* Wl[5]; const float* bl[5]; const float* Wr[5];
    for (int i = 0; i < 5; ++i){
        Wl[i] = (const float*)d_in[3 + 3*i];
        bl[i] = (const float*)d_in[4 + 3*i];
        Wr[i] = (const float*)d_in[5 + 3*i];
    }
    const float* pw1 = (const float*)d_in[18]; const float* pb1 = (const float*)d_in[19];
    const float* pw2 = (const float*)d_in[20]; const float* pb2 = (const float*)d_in[21];
    const float* pw3 = (const float*)d_in[22]; const float* pb3 = (const float*)d_in[23];
    float* out = (float*)d_out;

    const int N  = in_sizes[2];
    const int E  = in_sizes[1] / 2;
    const int NG = out_size;
    const int* esrc = ei;
    const int* edst = ei + E;
    const int nbuck = (N + 63) >> BSHIFT;          // 1563
    const int nblk  = (E + EPB - 1) / EPB;         // 782

    // ---- workspace carve ----
    char* p = (char*)d_ws;
    auto carve = [&](size_t bytes)->void* {
        void* r = (void*)p;
        p += (bytes + 255) & ~(size_t)255;
        return r;
    };
    int*   deg     = (int*)  carve((size_t)N * 4);
    int*   row_ptr = (int*)  carve(((size_t)N + 1) * 4);
    int*   csum    = (int*)  carve(4096);
    int*   hist    = (int*)  carve((size_t)nblk * nbuck * 4);
    int*   Tb      = (int*)  carve((size_t)nbuck * 4);
    int*   tbase   = (int*)  carve(((size_t)nbuck + 1) * 4);
    float* invdeg  = (float*)carve((size_t)N * 4);
    int*   gstart  = (int*)  carve(((size_t)NG + 1) * 4);
    int*   srcs    = (int*)  carve((size_t)E * 4);
    unsigned short* xp    = (unsigned short*)carve((size_t)N * 16 * 2);
    unsigned short* xa    = (unsigned short*)carve((size_t)N * 32 * 2);
    unsigned short* agg16 = (unsigned short*)carve((size_t)N * ROWP * 2);
    unsigned short* hA16  = (unsigned short*)carve((size_t)N * ROWP * 2);
    unsigned short* hB16  = (unsigned short*)carve((size_t)N * ROWP * 2);
    unsigned char*  h8A   = (unsigned char*) carve((size_t)N * ROWP);
    unsigned char*  h8B   = (unsigned char*) carve((size_t)N * ROWP);
    unsigned short* wpack = (unsigned short*)carve((size_t)8 * PACK_ELEMS * 2);
    unsigned short* w1pack= (unsigned short*)carve((size_t)PACK1_ELEMS * 2);
    float* biasp   = (float*)carve((size_t)5 * ROWP * 4);
    float* gsum    = (float*)carve((size_t)NG * 1000 * 4);
    float* t1      = (float*)carve((size_t)NG * 500 * 4);
    float* t2      = (float*)carve((size_t)NG * 250 * 4);
    // pairs (E x 8 B = 25.6 MB) aliased onto agg16 (44.8 MB): pairs are dead
    // before k_agg200 first writes agg16.
    int2* pairs = (int2*)agg16;

    // ---- zero what must be zero ----
    hipMemsetAsync(gsum, 0, (size_t)NG * 1000 * 4, stream);

    // ---- packing ----
    k_pack_w<<<dim3(NT, KS, 8), 64, 0, stream>>>(
        Wl[1], Wr[1], Wl[2], Wr[2], Wl[3], Wr[3], Wl[4], Wr[4], wpack);
    k_pack_w1<<<NT, 64, 0, stream>>>(Wl[0], Wr[0], w1pack);
    k_pack_b<<<5, ROWP, 0, stream>>>(bl[0], bl[1], bl[2], bl[3], bl[4], biasp);
    k_pack_x<<<(N * 16 + 255) / 256, 256, 0, stream>>>(x, xp, xa, N);

    // ---- binned CSR build (no hot global atomics) ----
    k_bin_hist<<<nblk, 256, 0, stream>>>(edst, hist, E, nbuck);
    k_col_scan<<<(nbuck + 63) / 64, 256, 0, stream>>>(hist, Tb, nblk, nbuck);
    k_scan_t<<<1, 256, 0, stream>>>(Tb, tbase, nbuck);
    k_bin_scatter<<<nblk, 256, 0, stream>>>(esrc, edst, hist, tbase, pairs, E, nbuck);
    k_bucket_deg<<<nbuck, 256, 0, stream>>>(pairs, tbase, deg, N);
    int nchunks = (N + 1023) / 1024;
    k_scan_sums<<<nchunks, 256, 0, stream>>>(deg, csum, N);
    k_scan_top<<<1, 64, 0, stream>>>(csum, nchunks);
    k_scan_apply<<<nchunks, 256, 0, stream>>>(deg, csum, row_ptr, N, E);
    k_inv_deg<<<(N + 255) / 256, 256, 0, stream>>>(deg, invdeg, N);
    k_place<<<nbuck, 256, 0, stream>>>(pairs, tbase, row_ptr, srcs, N);

    // ---- graph starts ----
    k_gstart_init<<<(NG + 256) / 256, 256, 0, stream>>>(gstart, N, NG);
    k_gstart_mark<<<(N + 255) / 256, 256, 0, stream>>>(batch, gstart, N);
    k_gstart_fix<<<1, 64, 0, stream>>>(gstart, N, NG);

    // ---- layer 1 (bf16 MFMA over K=32 = [agg11 | x11]) ----
    int gb = (N + 63) / 64;
    int gb2 = (N + 127) / 128;
    k_agg11<<<(N + 7) / 8, 256, 0, stream>>>(xp, row_ptr, srcs, invdeg, xa, N);
    k_layer1_mfma<<<gb, 256, 0, stream>>>(xa, w1pack, biasp, hA16, N);
    k_pool<<<dim3(NG, 8), 256, 0, stream>>>(hA16, gstart, gsum, 0, h8A);

    // ---- layers 2..5 (fp8 gather + bf16 MFMA, 32 rows/wave) ----
    unsigned short* hc = hA16; unsigned short* hn = hB16;
    unsigned char*  f8c = h8A; unsigned char*  f8n = h8B;
    int ab = (N + 3) / 4;
    for (int L = 1; L < 5; ++L){
        k_agg200<<<ab, 256, 0, stream>>>(f8c, row_ptr, srcs, invdeg, agg16, N);
        const unsigned short* Wlp = wpack + (size_t)((L-1)*2 + 0) * PACK_ELEMS;
        const unsigned short* Wrp = wpack + (size_t)((L-1)*2 + 1) * PACK_ELEMS;
        k_sage_mfma<<<gb2, 256, 0, stream>>>(agg16, hc, Wlp, Wrp,
                                             biasp + L * ROWP, hn, N);
        k_pool<<<dim3(NG, 8), 256, 0, stream>>>(hn, gstart, gsum, 200 * L, f8n);
        unsigned short* t = hc; hc = hn; hn = t;
        unsigned char*  t8 = f8c; f8c = f8n; f8n = t8;
    }

    // ---- pool finalize + MLP head ----
    k_pool_finalize<<<NG, 256, 0, stream>>>(gsum, gstart, NG);
    k_mlp<<<NG, 256, 0, stream>>>(gsum, pw1, pb1, t1, 1000, 500);
    k_mlp<<<NG, 256, 0, stream>>>(t1, pw2, pb2, t2, 500, 250);
    k_mlp3<<<1, 256, 0, stream>>>(t2, pw3, pb3, out, NG);
}

// Round 11
// 1616.550 us; speedup vs baseline: 1.3671x; 1.3671x over previous
//
#include <hip/hip_runtime.h>
#include <math.h>

typedef __attribute__((ext_vector_type(8))) short bf16x8;
typedef __attribute__((ext_vector_type(4))) float floatx4;
typedef __attribute__((ext_vector_type(2))) float floatx2;

#define ROWP 224          // padded row length (elements) for h/agg bf16 buffers
#define NT 14             // 14 x 16 = 224 output cols (200 real + pad)
#define KS 7              // 7 x 32 = 224 K (200 real + pad)
#define PACK_ELEMS (NT*KS*64*8)   // elements per packed weight matrix (layers 2..5)
#define PACK1_ELEMS (NT*64*8)     // layer-1 packed weight (K=32)
#define BSHIFT 6          // 64 nodes per CSR bucket
#define EPB 4096          // edges per binning block
#define MAXBUCK 1600      // LDS capacity for bucket arrays (>= nbuck=1563)

__device__ __forceinline__ unsigned short f2bf(float f){
    union { float f; unsigned u; } v; v.f = f;
    unsigned r = v.u + 0x7FFF + ((v.u >> 16) & 1);
    return (unsigned short)(r >> 16);
}
__device__ __forceinline__ float bf2f(unsigned short u){
    union { unsigned u; float f; } v; v.u = ((unsigned)u) << 16;
    return v.f;
}

// ============================ binned CSR build (no hot global atomics) ============================

__global__ __launch_bounds__(256) void k_bin_hist(
    const int* __restrict__ dst, int* __restrict__ hist, int E, int nbuck)
{
    __shared__ int lh[MAXBUCK];
    for (int i = threadIdx.x; i < nbuck; i += 256) lh[i] = 0;
    __syncthreads();
    int base = blockIdx.x * EPB;
    #pragma unroll
    for (int k = 0; k < EPB / 256; ++k){
        int e = base + k * 256 + threadIdx.x;
        if (e < E) atomicAdd(&lh[dst[e] >> BSHIFT], 1);
    }
    __syncthreads();
    for (int i = threadIdx.x; i < nbuck; i += 256)
        hist[(size_t)blockIdx.x * nbuck + i] = lh[i];
}

__global__ __launch_bounds__(256) void k_col_scan(
    int* __restrict__ hist, int* __restrict__ T, int nblk, int nbuck)
{
    __shared__ int part[4][64];
    int w = threadIdx.x >> 6, l = threadIdx.x & 63;
    int b = blockIdx.x * 64 + l;
    int chunk = (nblk + 3) >> 2;
    int j0 = w * chunk, j1 = j0 + chunk; if (j1 > nblk) j1 = nblk;
    int s = 0;
    if (b < nbuck)
        for (int j = j0; j < j1; ++j) s += hist[(size_t)j * nbuck + b];
    part[w][l] = s;
    __syncthreads();
    if (b < nbuck){
        int run = 0;
        for (int w2 = 0; w2 < w; ++w2) run += part[w2][l];
        for (int j = j0; j < j1; ++j){
            int v = hist[(size_t)j * nbuck + b];
            hist[(size_t)j * nbuck + b] = run;
            run += v;
        }
        if (w == 3) T[b] = part[0][l] + part[1][l] + part[2][l] + part[3][l];
    }
}

__global__ __launch_bounds__(256) void k_scan_t(
    const int* __restrict__ T, int* __restrict__ tbase, int nbuck)
{
    __shared__ int ts[256];
    int t = threadIdx.x;
    int v[8]; int s = 0;
    int base = t * 8;
    #pragma unroll
    for (int k = 0; k < 8; ++k){
        int idx = base + k;
        v[k] = (idx < nbuck) ? T[idx] : 0;
        s += v[k];
    }
    ts[t] = s; __syncthreads();
    #pragma unroll
    for (int off = 1; off < 256; off <<= 1){
        int p = (t >= off) ? ts[t - off] : 0;
        __syncthreads();
        ts[t] += p;
        __syncthreads();
    }
    int run = ts[t] - s;
    #pragma unroll
    for (int k = 0; k < 8; ++k){
        int idx = base + k;
        if (idx < nbuck) tbase[idx] = run;
        run += v[k];
    }
    if (t == 255) tbase[nbuck] = ts[255];
}

__global__ __launch_bounds__(256) void k_bin_scatter(
    const int* __restrict__ src, const int* __restrict__ dst,
    const int* __restrict__ off, const int* __restrict__ tbase,
    int2* __restrict__ pairs, int E, int nbuck)
{
    __shared__ int lbase[MAXBUCK];
    __shared__ int lc[MAXBUCK];
    for (int i = threadIdx.x; i < nbuck; i += 256){
        lbase[i] = off[(size_t)blockIdx.x * nbuck + i] + tbase[i];
        lc[i] = 0;
    }
    __syncthreads();
    int base = blockIdx.x * EPB;
    #pragma unroll
    for (int k = 0; k < EPB / 256; ++k){
        int e = base + k * 256 + threadIdx.x;
        if (e < E){
            int d = dst[e];
            int b = d >> BSHIFT;
            int r = atomicAdd(&lc[b], 1);
            pairs[lbase[b] + r] = make_int2(src[e], d);
        }
    }
}

__global__ __launch_bounds__(256) void k_bucket_deg(
    const int2* __restrict__ pairs, const int* __restrict__ tbase,
    int* __restrict__ deg, int N)
{
    __shared__ int ld[64];
    int b = blockIdx.x;
    if (threadIdx.x < 64) ld[threadIdx.x] = 0;
    __syncthreads();
    int pb = tbase[b], pe = tbase[b + 1];
    for (int e = pb + threadIdx.x; e < pe; e += 256)
        atomicAdd(&ld[pairs[e].y & 63], 1);
    __syncthreads();
    if (threadIdx.x < 64){
        int node = (b << BSHIFT) + threadIdx.x;
        if (node < N) deg[node] = ld[threadIdx.x];
    }
}

__global__ __launch_bounds__(256) void k_place(
    const int2* __restrict__ pairs, const int* __restrict__ tbase,
    const int* __restrict__ row_ptr, int* __restrict__ srcs, int N)
{
    __shared__ int lrp[64];
    __shared__ int lcur[64];
    int b = blockIdx.x;
    if (threadIdx.x < 64){
        int node = (b << BSHIFT) + threadIdx.x;
        lrp[threadIdx.x] = (node < N) ? row_ptr[node] : 0;
        lcur[threadIdx.x] = 0;
    }
    __syncthreads();
    int pb = tbase[b], pe = tbase[b + 1];
    for (int e = pb + threadIdx.x; e < pe; e += 256){
        int2 pr = pairs[e];
        int li = pr.y & 63;
        int r = atomicAdd(&lcur[li], 1);
        srcs[lrp[li] + r] = pr.x;
    }
}

// ============================ row_ptr scan (over deg) ============================

__global__ void k_scan_sums(const int* __restrict__ deg, int* __restrict__ csum, int N){
    __shared__ int sd[256];
    int base = blockIdx.x * 1024;
    int s = 0;
    for (int i = threadIdx.x; i < 1024; i += 256){
        int idx = base + i;
        s += (idx < N) ? deg[idx] : 0;
    }
    sd[threadIdx.x] = s; __syncthreads();
    for (int off = 128; off > 0; off >>= 1){
        if (threadIdx.x < off) sd[threadIdx.x] += sd[threadIdx.x + off];
        __syncthreads();
    }
    if (threadIdx.x == 0) csum[blockIdx.x] = sd[0];
}

__global__ void k_scan_top(int* __restrict__ csum, int n){
    if (blockIdx.x == 0 && threadIdx.x == 0){
        int run = 0;
        for (int i = 0; i < n; ++i){ int v = csum[i]; csum[i] = run; run += v; }
    }
}

__global__ void k_scan_apply(const int* __restrict__ deg, const int* __restrict__ csum,
                             int* __restrict__ row_ptr, int N, int E){
    __shared__ int ts[256];
    int base = blockIdx.x * 1024 + threadIdx.x * 4;
    int v[4]; int s = 0;
    #pragma unroll
    for (int j = 0; j < 4; ++j){
        int idx = base + j;
        v[j] = (idx < N) ? deg[idx] : 0;
        s += v[j];
    }
    ts[threadIdx.x] = s; __syncthreads();
    #pragma unroll
    for (int off = 1; off < 256; off <<= 1){
        int t = (threadIdx.x >= off) ? ts[threadIdx.x - off] : 0;
        __syncthreads();
        ts[threadIdx.x] += t;
        __syncthreads();
    }
    int excl = ts[threadIdx.x] - s + csum[blockIdx.x];
    #pragma unroll
    for (int j = 0; j < 4; ++j){
        int idx = base + j;
        if (idx < N) row_ptr[idx] = excl;
        excl += v[j];
    }
    if (blockIdx.x == 0 && threadIdx.x == 0) row_ptr[N] = E;
}

__global__ void k_inv_deg(const int* __restrict__ deg, float* __restrict__ inv_deg, int N){
    int i = blockIdx.x * blockDim.x + threadIdx.x;
    if (i < N) inv_deg[i] = 1.0f / fmaxf((float)deg[i], 1.0f);
}

// ============================ graph segment starts ============================

__global__ void k_gstart_init(int* __restrict__ gstart, int N, int NG){
    int g = blockIdx.x * blockDim.x + threadIdx.x;
    if (g <= NG) gstart[g] = N;
}

__global__ void k_gstart_mark(const int* __restrict__ batch, int* __restrict__ gstart, int N){
    int i = blockIdx.x * blockDim.x + threadIdx.x;
    if (i < N){
        int b = batch[i];
        if (i == 0 || batch[i-1] != b) atomicMin(&gstart[b], i);
    }
}

__global__ void k_gstart_fix(int* __restrict__ gstart, int N, int NG){
    if (blockIdx.x == 0 && threadIdx.x == 0){
        for (int g = NG - 1; g >= 0; --g)
            if (gstart[g] == N) gstart[g] = gstart[g+1];
    }
}

// ============================ weight / bias / x packing ============================

__global__ void k_pack_w(const float* W0, const float* W1, const float* W2, const float* W3,
                         const float* W4, const float* W5, const float* W6, const float* W7,
                         unsigned short* __restrict__ out){
    const float* Ws[8] = {W0,W1,W2,W3,W4,W5,W6,W7};
    const float* W = Ws[blockIdx.z];
    int lane = threadIdx.x;
    int n  = blockIdx.x * 16 + (lane & 15);
    int k0 = blockIdx.y * 32 + (lane >> 4) * 8;
    unsigned short v[8];
    #pragma unroll
    for (int j = 0; j < 8; ++j){
        int k = k0 + j;
        float f = (n < 200 && k < 200) ? W[n * 200 + k] : 0.f;
        v[j] = f2bf(f);
    }
    uint4 u;
    u.x = (unsigned)v[0] | ((unsigned)v[1] << 16);
    u.y = (unsigned)v[2] | ((unsigned)v[3] << 16);
    u.z = (unsigned)v[4] | ((unsigned)v[5] << 16);
    u.w = (unsigned)v[6] | ((unsigned)v[7] << 16);
    size_t off = ((((size_t)blockIdx.z * NT + blockIdx.x) * KS + blockIdx.y) * 64 + lane) * 8;
    *reinterpret_cast<uint4*>(out + off) = u;
}

// layer-1: pack concatenated [Wl1 (K 0..10) | pad | Wr1 (K 16..26) | pad] 224x32
__global__ void k_pack_w1(const float* __restrict__ Wl, const float* __restrict__ Wr,
                          unsigned short* __restrict__ out){
    int lane = threadIdx.x;
    int n  = blockIdx.x * 16 + (lane & 15);
    int k0 = (lane >> 4) * 8;
    unsigned short v[8];
    #pragma unroll
    for (int j = 0; j < 8; ++j){
        int k = k0 + j;
        float f = 0.f;
        if (n < 200){
            if (k < 11)                 f = Wl[n * 11 + k];
            else if (k >= 16 && k < 27) f = Wr[n * 11 + (k - 16)];
        }
        v[j] = f2bf(f);
    }
    uint4 u;
    u.x = (unsigned)v[0] | ((unsigned)v[1] << 16);
    u.y = (unsigned)v[2] | ((unsigned)v[3] << 16);
    u.z = (unsigned)v[4] | ((unsigned)v[5] << 16);
    u.w = (unsigned)v[6] | ((unsigned)v[7] << 16);
    size_t off = ((size_t)blockIdx.x * 64 + lane) * 8;
    *reinterpret_cast<uint4*>(out + off) = u;
}

__global__ void k_pack_b(const float* b0, const float* b1, const float* b2, const float* b3,
                         const float* b4, float* __restrict__ out){
    const float* bs[5] = {b0,b1,b2,b3,b4};
    int l = blockIdx.x, c = threadIdx.x;
    if (c < ROWP) out[l * ROWP + c] = (c < 200) ? bs[l][c] : 0.f;
}

__global__ void k_pack_x(const float* __restrict__ x, unsigned short* __restrict__ xp,
                         unsigned short* __restrict__ xa, int N){
    int i = blockIdx.x * blockDim.x + threadIdx.x;
    int node = i >> 4, c = i & 15;
    if (node < N){
        unsigned short v = (c < 11) ? f2bf(x[(size_t)node * 11 + c]) : 0;
        xp[i] = v;
        xa[(size_t)node * 32 + 16 + c] = v;
    }
}

// ============================ aggregation ============================

// K=11 edge-parallel: half-wave (32 lanes) per node, one edge per lane.
__global__ __launch_bounds__(256) void k_agg11(
    const unsigned short* __restrict__ xp, const int* __restrict__ row_ptr,
    const int* __restrict__ srcs, const float* __restrict__ inv_deg,
    unsigned short* __restrict__ xa, int N)
{
    int half = threadIdx.x >> 5;              // 0..7
    int node = blockIdx.x * 8 + half;
    int l = threadIdx.x & 31;
    if (node >= N) return;
    int beg = row_ptr[node], end = row_ptr[node + 1];

    float acc[12];
    #pragma unroll
    for (int i = 0; i < 12; ++i) acc[i] = 0.f;

    const uint4* x4 = reinterpret_cast<const uint4*>(xp);
    const uint2* x2 = reinterpret_cast<const uint2*>(xp);
    for (int e = beg + l; e < end; e += 32){
        int sn = srcs[e];
        uint4 a = x4[(size_t)sn * 2];
        uint2 b = x2[(size_t)sn * 4 + 2];
        union { unsigned u; float f; } c;
        c.u = a.x << 16;         acc[0] += c.f;
        c.u = a.x & 0xffff0000u; acc[1] += c.f;
        c.u = a.y << 16;         acc[2] += c.f;
        c.u = a.y & 0xffff0000u; acc[3] += c.f;
        c.u = a.z << 16;         acc[4] += c.f;
        c.u = a.z & 0xffff0000u; acc[5] += c.f;
        c.u = a.w << 16;         acc[6] += c.f;
        c.u = a.w & 0xffff0000u; acc[7] += c.f;
        c.u = b.x << 16;         acc[8] += c.f;
        c.u = b.x & 0xffff0000u; acc[9] += c.f;
        c.u = b.y << 16;         acc[10] += c.f;
        c.u = b.y & 0xffff0000u; acc[11] += c.f;
    }

    #pragma unroll
    for (int i = 0; i < 11; ++i){
        acc[i] += __shfl_xor(acc[i], 1, 64);
        acc[i] += __shfl_xor(acc[i], 2, 64);
        acc[i] += __shfl_xor(acc[i], 4, 64);
        acc[i] += __shfl_xor(acc[i], 8, 64);
        acc[i] += __shfl_xor(acc[i], 16, 64);
    }

    if (l == 0){
        float id = inv_deg[node];
        unsigned short b[12];
        #pragma unroll
        for (int i = 0; i < 11; ++i) b[i] = f2bf(acc[i] * id);
        b[11] = 0;
        uint4 o0, o1;
        o0.x = (unsigned)b[0] | ((unsigned)b[1] << 16);
        o0.y = (unsigned)b[2] | ((unsigned)b[3] << 16);
        o0.z = (unsigned)b[4] | ((unsigned)b[5] << 16);
        o0.w = (unsigned)b[6] | ((unsigned)b[7] << 16);
        o1.x = (unsigned)b[8] | ((unsigned)b[9] << 16);
        o1.y = (unsigned)b[10] | ((unsigned)b[11] << 16);
        o1.z = 0u; o1.w = 0u;
        uint4* dst4 = reinterpret_cast<uint4*>(xa + (size_t)node * 32);
        dst4[0] = o0;
        dst4[1] = o1;
    }
}

// fp8 gather-aggregate (layers 2..5). One wave per dst node.
__device__ __forceinline__ void accum_fp8(float* acc, uint4 u){
    floatx2 f;
    f = __builtin_amdgcn_cvt_pk_f32_fp8((int)u.x, false); acc[0] += f[0];  acc[1] += f[1];
    f = __builtin_amdgcn_cvt_pk_f32_fp8((int)u.x, true ); acc[2] += f[0];  acc[3] += f[1];
    f = __builtin_amdgcn_cvt_pk_f32_fp8((int)u.y, false); acc[4] += f[0];  acc[5] += f[1];
    f = __builtin_amdgcn_cvt_pk_f32_fp8((int)u.y, true ); acc[6] += f[0];  acc[7] += f[1];
    f = __builtin_amdgcn_cvt_pk_f32_fp8((int)u.z, false); acc[8] += f[0];  acc[9] += f[1];
    f = __builtin_amdgcn_cvt_pk_f32_fp8((int)u.z, true ); acc[10] += f[0]; acc[11] += f[1];
    f = __builtin_amdgcn_cvt_pk_f32_fp8((int)u.w, false); acc[12] += f[0]; acc[13] += f[1];
    f = __builtin_amdgcn_cvt_pk_f32_fp8((int)u.w, true ); acc[14] += f[0]; acc[15] += f[1];
}

__global__ __launch_bounds__(256) void k_agg200(
    const unsigned char* __restrict__ h8, const int* __restrict__ row_ptr,
    const int* __restrict__ srcs, const float* __restrict__ inv_deg,
    unsigned short* __restrict__ agg, int N)
{
    int node = blockIdx.x * 4 + (threadIdx.x >> 6);
    int lane = threadIdx.x & 63;
    if (node >= N) return;
    int g = lane >> 4;    // group 0..3
    int l = lane & 15;    // lane-in-group; active if l < 14
    int beg = row_ptr[node], end = row_ptr[node + 1];

    float acc[16];
    #pragma unroll
    for (int i = 0; i < 16; ++i) acc[i] = 0.f;

    if (l < 14){
        const uint4* h4 = reinterpret_cast<const uint4*>(h8);
        int e = beg + g;
        for (; e + 4 < end; e += 8){
            int sa = srcs[e];
            int sb = srcs[e + 4];
            uint4 ua = h4[(size_t)sa * 14 + l];
            uint4 ub = h4[(size_t)sb * 14 + l];
            accum_fp8(acc, ua);
            accum_fp8(acc, ub);
        }
        if (e < end){
            int sa = srcs[e];
            uint4 ua = h4[(size_t)sa * 14 + l];
            accum_fp8(acc, ua);
        }
    }

    #pragma unroll
    for (int i = 0; i < 16; ++i){
        acc[i] += __shfl_xor(acc[i], 32, 64);
        acc[i] += __shfl_xor(acc[i], 16, 64);
    }

    if (g == 0 && l < 14){
        float id = inv_deg[node];
        unsigned d[8];
        #pragma unroll
        for (int i = 0; i < 8; ++i){
            d[i] = (unsigned)f2bf(acc[2*i] * id) | ((unsigned)f2bf(acc[2*i+1] * id) << 16);
        }
        uint4* a4 = reinterpret_cast<uint4*>(agg);
        size_t base = (size_t)node * 28 + (size_t)l * 2;
        uint4 o0; o0.x = d[0]; o0.y = d[1]; o0.z = d[2]; o0.w = d[3];
        uint4 o1; o1.x = d[4]; o1.y = d[5]; o1.z = d[6]; o1.w = d[7];
        a4[base] = o0;
        a4[base + 1] = o1;
    }
}

// ============================ layer-1 MFMA (K=32: [agg11 | x11]) ============================

__global__ __launch_bounds__(256) void k_layer1_mfma(
    const unsigned short* __restrict__ xa, const unsigned short* __restrict__ W1p,
    const float* __restrict__ biasp, unsigned short* __restrict__ outp, int M)
{
    const int wave = threadIdx.x >> 6;
    const int lane = threadIdx.x & 63;
    const int n = lane & 15;
    const int q = lane >> 4;
    int row = blockIdx.x * 64 + wave * 16 + n;
    int rowc = row < M ? row : (M - 1);

    bf16x8 a = *reinterpret_cast<const bf16x8*>(xa + (size_t)rowc * 32 + q * 8);

    floatx4 acc[NT];
    #pragma unroll
    for (int nt = 0; nt < NT; ++nt){
        bf16x8 b = *reinterpret_cast<const bf16x8*>(W1p + ((size_t)nt * 64 + lane) * 8);
        acc[nt] = __builtin_amdgcn_mfma_f32_16x16x32_bf16(a, b, (floatx4){0.f,0.f,0.f,0.f}, 0, 0, 0);
    }

    int r0 = blockIdx.x * 64 + wave * 16 + q * 4;
    #pragma unroll
    for (int nt = 0; nt < NT; ++nt){
        float bsv = biasp[nt * 16 + n];
        #pragma unroll
        for (int r = 0; r < 4; ++r){
            int rr = r0 + r;
            if (rr < M){
                float v = fmaxf(acc[nt][r] + bsv, 0.f);
                outp[(size_t)rr * ROWP + nt * 16 + n] = f2bf(v);
            }
        }
    }
}

// ============================ MFMA SAGE GEMM (layers 2..5) ============================
// Round-7 geometry (64 rows/block, 16 rows/wave, 6252 waves) + LDS-staged B:
// each (phase,ks) 14 KB B-slab is loaded ONCE per block (4x less B L2-traffic
// than r7), double-buffered; MFMA feeds from ~12cy ds_read_b128 instead of
// ~200-300cy global loads. Single acc set (56 regs) + NO min-wave launch pin:
// r9's spill came from (256,3) capping the unified VGPR/AGPR budget at ~170
// with 112 AGPRs of accumulators.
__global__ __launch_bounds__(256) void k_sage_mfma(
    const unsigned short* __restrict__ Aagg, const unsigned short* __restrict__ Ah,
    const unsigned short* __restrict__ Wlp, const unsigned short* __restrict__ Wrp,
    const float* __restrict__ biasp, unsigned short* __restrict__ outp, int M)
{
    __shared__ __align__(16) unsigned short lb[2][NT * 512];   // 2 x 14 KB
    const int wave = threadIdx.x >> 6;
    const int lane = threadIdx.x & 63;
    const int n = lane & 15;
    const int q = lane >> 4;
    int row = blockIdx.x * 64 + wave * 16 + n;
    int rowc = row < M ? row : (M - 1);

    floatx4 acc[NT];
    #pragma unroll
    for (int nt = 0; nt < NT; ++nt) acc[nt] = (floatx4){0.f, 0.f, 0.f, 0.f};

    const unsigned short* Wp[2] = {Wlp, Wrp};
    const unsigned short* Ap[2] = {Aagg, Ah};

    // stage slab 0 (phase 0, ks 0) into buffer 0
    #pragma unroll
    for (int j = 0; j < 4; ++j){
        int c = j * 4 + wave;
        if (c < NT){
            *reinterpret_cast<uint4*>(&lb[0][c * 512 + lane * 8]) =
                *reinterpret_cast<const uint4*>(Wlp + ((size_t)(c * KS) * 64 + lane) * 8);
        }
    }
    __syncthreads();

    int buf = 0;
    #pragma unroll
    for (int phase = 0; phase < 2; ++phase){
        const unsigned short* arow = Ap[phase] + (size_t)rowc * ROWP + q * 8;
        #pragma unroll
        for (int ks = 0; ks < KS; ++ks){
            // prefetch next slab into the other buffer (safe: barrier at end of
            // the PREVIOUS iteration guaranteed everyone finished reading it)
            int ns = phase * KS + ks + 1;
            if (ns < 2 * KS){
                const unsigned short* W = Wp[ns / KS];
                int nks = ns % KS;
                #pragma unroll
                for (int j = 0; j < 4; ++j){
                    int c = j * 4 + wave;
                    if (c < NT){
                        *reinterpret_cast<uint4*>(&lb[buf ^ 1][c * 512 + lane * 8]) =
                            *reinterpret_cast<const uint4*>(W + ((size_t)(c * KS + nks) * 64 + lane) * 8);
                    }
                }
            }
            bf16x8 a = *reinterpret_cast<const bf16x8*>(arow + ks * 32);
            #pragma unroll
            for (int nt = 0; nt < NT; ++nt){
                bf16x8 b = *reinterpret_cast<const bf16x8*>(&lb[buf][nt * 512 + lane * 8]);
                acc[nt] = __builtin_amdgcn_mfma_f32_16x16x32_bf16(a, b, acc[nt], 0, 0, 0);
            }
            __syncthreads();
            buf ^= 1;
        }
    }

    // epilogue: C/D layout col=lane&15, row=(lane>>4)*4+reg
    int r0 = blockIdx.x * 64 + wave * 16 + q * 4;
    #pragma unroll
    for (int nt = 0; nt < NT; ++nt){
        float bsv = biasp[nt * 16 + n];
        #pragma unroll
        for (int r = 0; r < 4; ++r){
            int rr = r0 + r;
            if (rr < M){
                float v = fmaxf(acc[nt][r] + bsv, 0.f);
                outp[(size_t)rr * ROWP + nt * 16 + n] = f2bf(v);
            }
        }
    }
}

// ============================ pooling + fp8 shadow write ============================

__global__ __launch_bounds__(256) void k_pool(
    const unsigned short* __restrict__ h, const int* __restrict__ gstart,
    float* __restrict__ gsum, int col_off, unsigned char* __restrict__ h8)
{
    int g = blockIdx.x;
    int beg = gstart[g], end = gstart[g+1];
    int len = end - beg;
    if (len <= 0) return;
    int sub = threadIdx.x >> 6;                 // 0..3
    int t   = threadIdx.x & 63;                 // lane
    if (t >= 56) return;
    int pidx = blockIdx.y * 4 + sub;            // 0..31
    int chunk = (len + 31) >> 5;
    int rb = beg + pidx * chunk;
    int re = rb + chunk; if (re > end) re = end;
    if (rb >= re) return;
    int c0 = t * 4;

    float s0 = 0.f, s1 = 0.f, s2 = 0.f, s3 = 0.f;
    for (int r = rb; r < re; ++r){
        uint2 u = *reinterpret_cast<const uint2*>(h + (size_t)r * ROWP + c0);
        union { unsigned u; float f; } c;
        float v0, v1, v2, v3;
        c.u = u.x << 16;         v0 = c.f;
        c.u = u.x & 0xffff0000u; v1 = c.f;
        c.u = u.y << 16;         v2 = c.f;
        c.u = u.y & 0xffff0000u; v3 = c.f;
        s0 += v0; s1 += v1; s2 += v2; s3 += v3;
        int pk = __builtin_amdgcn_cvt_pk_fp8_f32(v0, v1, 0, false);
        pk = __builtin_amdgcn_cvt_pk_fp8_f32(v2, v3, pk, true);
        *reinterpret_cast<unsigned*>(h8 + (size_t)r * ROWP + c0) = (unsigned)pk;
    }
    if (c0 < 200){
        float* gs = &gsum[(size_t)g * 1000 + col_off + c0];
        atomicAdd(gs + 0, s0);
        atomicAdd(gs + 1, s1);
        atomicAdd(gs + 2, s2);
        atomicAdd(gs + 3, s3);
    }
}

__global__ __launch_bounds__(256) void k_pool_finalize(
    float* __restrict__ gsum, const int* __restrict__ gstart, int NG)
{
    int g = blockIdx.x;
    int cnt = gstart[g+1] - gstart[g];
    float inv = 1.0f / fmaxf((float)cnt, 1.0f);
    for (int i = threadIdx.x; i < 1000; i += 256)
        gsum[(size_t)g * 1000 + i] *= inv;
}

// ============================ MLP head (fp32) ============================

__global__ __launch_bounds__(256) void k_mlp(
    const float* __restrict__ in, const float* __restrict__ W,
    const float* __restrict__ b, float* __restrict__ outp, int Fin, int Fout)
{
    __shared__ __align__(16) float row[1000];
    int g = blockIdx.x;
    for (int i = threadIdx.x; i < Fin; i += 256) row[i] = in[(size_t)g * Fin + i];
    __syncthreads();
    int f4 = Fin >> 2;
    for (int c = threadIdx.x; c < Fout; c += 256){
        const float4* w4 = reinterpret_cast<const float4*>(W + (size_t)c * Fin);
        const float4* r4 = reinterpret_cast<const float4*>(row);
        float s = b[c];
        for (int k = 0; k < f4; ++k){
            float4 wv = w4[k]; float4 rv = r4[k];
            s = fmaf(wv.x, rv.x, s);
            s = fmaf(wv.y, rv.y, s);
            s = fmaf(wv.z, rv.z, s);
            s = fmaf(wv.w, rv.w, s);
        }
        outp[(size_t)g * Fout + c] = s;
    }
}

__global__ void k_mlp3(const float* __restrict__ in, const float* __restrict__ W,
                       const float* __restrict__ b, float* __restrict__ outp, int NG)
{
    int g = blockIdx.x * blockDim.x + threadIdx.x;
    if (g < NG){
        float s = b[0];
        const float* r = in + (size_t)g * 250;
        for (int k = 0; k < 250; ++k) s = fmaf(r[k], W[k], s);
        outp[g] = 1.0f / (1.0f + expf(-s));
    }
}

// ============================ launch ============================

extern "C" void kernel_launch(void* const* d_in, const int* in_sizes, int n_in,
                              void* d_out, int out_size, void* d_ws, size_t ws_size,
                              hipStream_t stream)
{
    const float* x    = (const float*)d_in[0];
    const int*   ei   = (const int*)d_in[1];
    const int*   batch= (const int*)d_in[2];
    const float* Wl[5]; const float* bl[5]; const float* Wr[5];
    for (int i = 0; i < 5; ++i){
        Wl[i] = (const float*)d_in[3 + 3*i];
        bl[i] = (const float*)d_in[4 + 3*i];
        Wr[i] = (const float*)d_in[5 + 3*i];
    }
    const float* pw1 = (const float*)d_in[18]; const float* pb1 = (const float*)d_in[19];
    const float* pw2 = (const float*)d_in[20]; const float* pb2 = (const float*)d_in[21];
    const float* pw3 = (const float*)d_in[22]; const float* pb3 = (const float*)d_in[23];
    float* out = (float*)d_out;

    const int N  = in_sizes[2];
    const int E  = in_sizes[1] / 2;
    const int NG = out_size;
    const int* esrc = ei;
    const int* edst = ei + E;
    const int nbuck = (N + 63) >> BSHIFT;          // 1563
    const int nblk  = (E + EPB - 1) / EPB;         // 782

    // ---- workspace carve ----
    char* p = (char*)d_ws;
    auto carve = [&](size_t bytes)->void* {
        void* r = (void*)p;
        p += (bytes + 255) & ~(size_t)255;
        return r;
    };
    int*   deg     = (int*)  carve((size_t)N * 4);
    int*   row_ptr = (int*)  carve(((size_t)N + 1) * 4);
    int*   csum    = (int*)  carve(4096);
    int*   hist    = (int*)  carve((size_t)nblk * nbuck * 4);
    int*   Tb      = (int*)  carve((size_t)nbuck * 4);
    int*   tbase   = (int*)  carve(((size_t)nbuck + 1) * 4);
    float* invdeg  = (float*)carve((size_t)N * 4);
    int*   gstart  = (int*)  carve(((size_t)NG + 1) * 4);
    int*   srcs    = (int*)  carve((size_t)E * 4);
    unsigned short* xp    = (unsigned short*)carve((size_t)N * 16 * 2);
    unsigned short* xa    = (unsigned short*)carve((size_t)N * 32 * 2);
    unsigned short* agg16 = (unsigned short*)carve((size_t)N * ROWP * 2);
    unsigned short* hA16  = (unsigned short*)carve((size_t)N * ROWP * 2);
    unsigned short* hB16  = (unsigned short*)carve((size_t)N * ROWP * 2);
    unsigned char*  h8A   = (unsigned char*) carve((size_t)N * ROWP);
    unsigned char*  h8B   = (unsigned char*) carve((size_t)N * ROWP);
    unsigned short* wpack = (unsigned short*)carve((size_t)8 * PACK_ELEMS * 2);
    unsigned short* w1pack= (unsigned short*)carve((size_t)PACK1_ELEMS * 2);
    float* biasp   = (float*)carve((size_t)5 * ROWP * 4);
    float* gsum    = (float*)carve((size_t)NG * 1000 * 4);
    float* t1      = (float*)carve((size_t)NG * 500 * 4);
    float* t2      = (float*)carve((size_t)NG * 250 * 4);
    // pairs (E x 8 B = 25.6 MB) aliased onto agg16 (44.8 MB): pairs are dead
    // before k_agg200 first writes agg16.
    int2* pairs = (int2*)agg16;

    // ---- zero what must be zero ----
    hipMemsetAsync(gsum, 0, (size_t)NG * 1000 * 4, stream);

    // ---- packing ----
    k_pack_w<<<dim3(NT, KS, 8), 64, 0, stream>>>(
        Wl[1], Wr[1], Wl[2], Wr[2], Wl[3], Wr[3], Wl[4], Wr[4], wpack);
    k_pack_w1<<<NT, 64, 0, stream>>>(Wl[0], Wr[0], w1pack);
    k_pack_b<<<5, ROWP, 0, stream>>>(bl[0], bl[1], bl[2], bl[3], bl[4], biasp);
    k_pack_x<<<(N * 16 + 255) / 256, 256, 0, stream>>>(x, xp, xa, N);

    // ---- binned CSR build (no hot global atomics) ----
    k_bin_hist<<<nblk, 256, 0, stream>>>(edst, hist, E, nbuck);
    k_col_scan<<<(nbuck + 63) / 64, 256, 0, stream>>>(hist, Tb, nblk, nbuck);
    k_scan_t<<<1, 256, 0, stream>>>(Tb, tbase, nbuck);
    k_bin_scatter<<<nblk, 256, 0, stream>>>(esrc, edst, hist, tbase, pairs, E, nbuck);
    k_bucket_deg<<<nbuck, 256, 0, stream>>>(pairs, tbase, deg, N);
    int nchunks = (N + 1023) / 1024;
    k_scan_sums<<<nchunks, 256, 0, stream>>>(deg, csum, N);
    k_scan_top<<<1, 64, 0, stream>>>(csum, nchunks);
    k_scan_apply<<<nchunks, 256, 0, stream>>>(deg, csum, row_ptr, N, E);
    k_inv_deg<<<(N + 255) / 256, 256, 0, stream>>>(deg, invdeg, N);
    k_place<<<nbuck, 256, 0, stream>>>(pairs, tbase, row_ptr, srcs, N);

    // ---- graph starts ----
    k_gstart_init<<<(NG + 256) / 256, 256, 0, stream>>>(gstart, N, NG);
    k_gstart_mark<<<(N + 255) / 256, 256, 0, stream>>>(batch, gstart, N);
    k_gstart_fix<<<1, 64, 0, stream>>>(gstart, N, NG);

    // ---- layer 1 (bf16 MFMA over K=32 = [agg11 | x11]) ----
    int gb = (N + 63) / 64;
    k_agg11<<<(N + 7) / 8, 256, 0, stream>>>(xp, row_ptr, srcs, invdeg, xa, N);
    k_layer1_mfma<<<gb, 256, 0, stream>>>(xa, w1pack, biasp, hA16, N);
    k_pool<<<dim3(NG, 8), 256, 0, stream>>>(hA16, gstart, gsum, 0, h8A);

    // ---- layers 2..5 (fp8 gather + LDS-staged bf16 MFMA) ----
    unsigned short* hc = hA16; unsigned short* hn = hB16;
    unsigned char*  f8c = h8A; unsigned char*  f8n = h8B;
    int ab = (N + 3) / 4;
    for (int L = 1; L < 5; ++L){
        k_agg200<<<ab, 256, 0, stream>>>(f8c, row_ptr, srcs, invdeg, agg16, N);
        const unsigned short* Wlp = wpack + (size_t)((L-1)*2 + 0) * PACK_ELEMS;
        const unsigned short* Wrp = wpack + (size_t)((L-1)*2 + 1) * PACK_ELEMS;
        k_sage_mfma<<<gb, 256, 0, stream>>>(agg16, hc, Wlp, Wrp,
                                            biasp + L * ROWP, hn, N);
        k_pool<<<dim3(NG, 8), 256, 0, stream>>>(hn, gstart, gsum, 200 * L, f8n);
        unsigned short* t = hc; hc = hn; hn = t;
        unsigned char*  t8 = f8c; f8c = f8n; f8n = t8;
    }

    // ---- pool finalize + MLP head ----
    k_pool_finalize<<<NG, 256, 0, stream>>>(gsum, gstart, NG);
    k_mlp<<<NG, 256, 0, stream>>>(gsum, pw1, pb1, t1, 1000, 500);
    k_mlp<<<NG, 256, 0, stream>>>(t1, pw2, pb2, t2, 500, 250);
    k_mlp3<<<1, 256, 0, stream>>>(t2, pw3, pb3, out, NG);
}

// Round 12
// 1429.312 us; speedup vs baseline: 1.5462x; 1.1310x over previous
//
#include <hip/hip_runtime.h>
#include <math.h>

typedef __attribute__((ext_vector_type(8))) short bf16x8;
typedef __attribute__((ext_vector_type(4))) float floatx4;
typedef __attribute__((ext_vector_type(2))) float floatx2;

#define ROWP 224          // padded row length (fp8 bytes) for h/agg buffers
#define NT 14             // 14 x 16 = 224 output cols (200 real + pad)
#define KS 7              // 7 x 32 = 224 K (200 real + pad)
#define PACK_BYTES (NT*KS*64*8)   // bytes per packed fp8 weight matrix (layers 2..5)
#define PACK1_BYTES (NT*64*8)     // layer-1 packed fp8 weight (K=32)
#define BSHIFT 6          // 64 nodes per CSR bucket
#define EPB 4096          // edges per binning block
#define MAXBUCK 1600      // LDS capacity for bucket arrays (>= nbuck=1563)

__device__ __forceinline__ unsigned short f2bf(float f){
    union { float f; unsigned u; } v; v.f = f;
    unsigned r = v.u + 0x7FFF + ((v.u >> 16) & 1);
    return (unsigned short)(r >> 16);
}
__device__ __forceinline__ unsigned pk4_fp8(float a, float b, float c, float d){
    int w = __builtin_amdgcn_cvt_pk_fp8_f32(a, b, 0, false);
    w = __builtin_amdgcn_cvt_pk_fp8_f32(c, d, w, true);
    return (unsigned)w;
}
__device__ __forceinline__ unsigned char b1_fp8(float a){
    int w = __builtin_amdgcn_cvt_pk_fp8_f32(a, a, 0, false);
    return (unsigned char)(w & 0xFF);
}

// ============================ binned CSR build (no hot global atomics) ============================

__global__ __launch_bounds__(256) void k_bin_hist(
    const int* __restrict__ dst, int* __restrict__ hist, int E, int nbuck)
{
    __shared__ int lh[MAXBUCK];
    for (int i = threadIdx.x; i < nbuck; i += 256) lh[i] = 0;
    __syncthreads();
    int base = blockIdx.x * EPB;
    #pragma unroll
    for (int k = 0; k < EPB / 256; ++k){
        int e = base + k * 256 + threadIdx.x;
        if (e < E) atomicAdd(&lh[dst[e] >> BSHIFT], 1);
    }
    __syncthreads();
    for (int i = threadIdx.x; i < nbuck; i += 256)
        hist[(size_t)blockIdx.x * nbuck + i] = lh[i];
}

__global__ __launch_bounds__(256) void k_col_scan(
    int* __restrict__ hist, int* __restrict__ T, int nblk, int nbuck)
{
    __shared__ int part[4][64];
    int w = threadIdx.x >> 6, l = threadIdx.x & 63;
    int b = blockIdx.x * 64 + l;
    int chunk = (nblk + 3) >> 2;
    int j0 = w * chunk, j1 = j0 + chunk; if (j1 > nblk) j1 = nblk;
    int s = 0;
    if (b < nbuck)
        for (int j = j0; j < j1; ++j) s += hist[(size_t)j * nbuck + b];
    part[w][l] = s;
    __syncthreads();
    if (b < nbuck){
        int run = 0;
        for (int w2 = 0; w2 < w; ++w2) run += part[w2][l];
        for (int j = j0; j < j1; ++j){
            int v = hist[(size_t)j * nbuck + b];
            hist[(size_t)j * nbuck + b] = run;
            run += v;
        }
        if (w == 3) T[b] = part[0][l] + part[1][l] + part[2][l] + part[3][l];
    }
}

__global__ __launch_bounds__(256) void k_scan_t(
    const int* __restrict__ T, int* __restrict__ tbase, int nbuck)
{
    __shared__ int ts[256];
    int t = threadIdx.x;
    int v[8]; int s = 0;
    int base = t * 8;
    #pragma unroll
    for (int k = 0; k < 8; ++k){
        int idx = base + k;
        v[k] = (idx < nbuck) ? T[idx] : 0;
        s += v[k];
    }
    ts[t] = s; __syncthreads();
    #pragma unroll
    for (int off = 1; off < 256; off <<= 1){
        int p = (t >= off) ? ts[t - off] : 0;
        __syncthreads();
        ts[t] += p;
        __syncthreads();
    }
    int run = ts[t] - s;
    #pragma unroll
    for (int k = 0; k < 8; ++k){
        int idx = base + k;
        if (idx < nbuck) tbase[idx] = run;
        run += v[k];
    }
    if (t == 255) tbase[nbuck] = ts[255];
}

__global__ __launch_bounds__(256) void k_bin_scatter(
    const int* __restrict__ src, const int* __restrict__ dst,
    const int* __restrict__ off, const int* __restrict__ tbase,
    int2* __restrict__ pairs, int E, int nbuck)
{
    __shared__ int lbase[MAXBUCK];
    __shared__ int lc[MAXBUCK];
    for (int i = threadIdx.x; i < nbuck; i += 256){
        lbase[i] = off[(size_t)blockIdx.x * nbuck + i] + tbase[i];
        lc[i] = 0;
    }
    __syncthreads();
    int base = blockIdx.x * EPB;
    #pragma unroll
    for (int k = 0; k < EPB / 256; ++k){
        int e = base + k * 256 + threadIdx.x;
        if (e < E){
            int d = dst[e];
            int b = d >> BSHIFT;
            int r = atomicAdd(&lc[b], 1);
            pairs[lbase[b] + r] = make_int2(src[e], d);
        }
    }
}

__global__ __launch_bounds__(256) void k_bucket_deg(
    const int2* __restrict__ pairs, const int* __restrict__ tbase,
    int* __restrict__ deg, int N)
{
    __shared__ int ld[64];
    int b = blockIdx.x;
    if (threadIdx.x < 64) ld[threadIdx.x] = 0;
    __syncthreads();
    int pb = tbase[b], pe = tbase[b + 1];
    for (int e = pb + threadIdx.x; e < pe; e += 256)
        atomicAdd(&ld[pairs[e].y & 63], 1);
    __syncthreads();
    if (threadIdx.x < 64){
        int node = (b << BSHIFT) + threadIdx.x;
        if (node < N) deg[node] = ld[threadIdx.x];
    }
}

__global__ __launch_bounds__(256) void k_place(
    const int2* __restrict__ pairs, const int* __restrict__ tbase,
    const int* __restrict__ row_ptr, int* __restrict__ srcs, int N)
{
    __shared__ int lrp[64];
    __shared__ int lcur[64];
    int b = blockIdx.x;
    if (threadIdx.x < 64){
        int node = (b << BSHIFT) + threadIdx.x;
        lrp[threadIdx.x] = (node < N) ? row_ptr[node] : 0;
        lcur[threadIdx.x] = 0;
    }
    __syncthreads();
    int pb = tbase[b], pe = tbase[b + 1];
    for (int e = pb + threadIdx.x; e < pe; e += 256){
        int2 pr = pairs[e];
        int li = pr.y & 63;
        int r = atomicAdd(&lcur[li], 1);
        srcs[lrp[li] + r] = pr.x;
    }
}

// ============================ row_ptr scan (over deg) ============================

__global__ void k_scan_sums(const int* __restrict__ deg, int* __restrict__ csum, int N){
    __shared__ int sd[256];
    int base = blockIdx.x * 1024;
    int s = 0;
    for (int i = threadIdx.x; i < 1024; i += 256){
        int idx = base + i;
        s += (idx < N) ? deg[idx] : 0;
    }
    sd[threadIdx.x] = s; __syncthreads();
    for (int off = 128; off > 0; off >>= 1){
        if (threadIdx.x < off) sd[threadIdx.x] += sd[threadIdx.x + off];
        __syncthreads();
    }
    if (threadIdx.x == 0) csum[blockIdx.x] = sd[0];
}

__global__ void k_scan_top(int* __restrict__ csum, int n){
    if (blockIdx.x == 0 && threadIdx.x == 0){
        int run = 0;
        for (int i = 0; i < n; ++i){ int v = csum[i]; csum[i] = run; run += v; }
    }
}

__global__ void k_scan_apply(const int* __restrict__ deg, const int* __restrict__ csum,
                             int* __restrict__ row_ptr, int N, int E){
    __shared__ int ts[256];
    int base = blockIdx.x * 1024 + threadIdx.x * 4;
    int v[4]; int s = 0;
    #pragma unroll
    for (int j = 0; j < 4; ++j){
        int idx = base + j;
        v[j] = (idx < N) ? deg[idx] : 0;
        s += v[j];
    }
    ts[threadIdx.x] = s; __syncthreads();
    #pragma unroll
    for (int off = 1; off < 256; off <<= 1){
        int t = (threadIdx.x >= off) ? ts[threadIdx.x - off] : 0;
        __syncthreads();
        ts[threadIdx.x] += t;
        __syncthreads();
    }
    int excl = ts[threadIdx.x] - s + csum[blockIdx.x];
    #pragma unroll
    for (int j = 0; j < 4; ++j){
        int idx = base + j;
        if (idx < N) row_ptr[idx] = excl;
        excl += v[j];
    }
    if (blockIdx.x == 0 && threadIdx.x == 0) row_ptr[N] = E;
}

__global__ void k_inv_deg(const int* __restrict__ deg, float* __restrict__ inv_deg, int N){
    int i = blockIdx.x * blockDim.x + threadIdx.x;
    if (i < N) inv_deg[i] = 1.0f / fmaxf((float)deg[i], 1.0f);
}

// ============================ graph segment starts ============================

__global__ void k_gstart_init(int* __restrict__ gstart, int N, int NG){
    int g = blockIdx.x * blockDim.x + threadIdx.x;
    if (g <= NG) gstart[g] = N;
}

__global__ void k_gstart_mark(const int* __restrict__ batch, int* __restrict__ gstart, int N){
    int i = blockIdx.x * blockDim.x + threadIdx.x;
    if (i < N){
        int b = batch[i];
        if (i == 0 || batch[i-1] != b) atomicMin(&gstart[b], i);
    }
}

__global__ void k_gstart_fix(int* __restrict__ gstart, int N, int NG){
    if (blockIdx.x == 0 && threadIdx.x == 0){
        for (int g = NG - 1; g >= 0; --g)
            if (gstart[g] == N) gstart[g] = gstart[g+1];
    }
}

// ============================ weight / bias / x packing (fp8) ============================

// pack W [200x200 fp32] -> fp8 B-frag order: byte(lane,j) = W[nt*16+(lane&15)][ks*32+(lane>>4)*8+j]
__global__ void k_pack_w(const float* W0, const float* W1, const float* W2, const float* W3,
                         const float* W4, const float* W5, const float* W6, const float* W7,
                         unsigned char* __restrict__ out){
    const float* Ws[8] = {W0,W1,W2,W3,W4,W5,W6,W7};
    const float* W = Ws[blockIdx.z];
    int lane = threadIdx.x;
    int n  = blockIdx.x * 16 + (lane & 15);
    int k0 = blockIdx.y * 32 + (lane >> 4) * 8;
    float f[8];
    #pragma unroll
    for (int j = 0; j < 8; ++j){
        int k = k0 + j;
        f[j] = (n < 200 && k < 200) ? W[n * 200 + k] : 0.f;
    }
    uint2 u;
    u.x = pk4_fp8(f[0], f[1], f[2], f[3]);
    u.y = pk4_fp8(f[4], f[5], f[6], f[7]);
    size_t off = ((((size_t)blockIdx.z * NT + blockIdx.x) * KS + blockIdx.y) * 64 + lane) * 8;
    *reinterpret_cast<uint2*>(out + off) = u;
}

// layer-1: [Wl1 (K 0..10) | pad | Wr1 (K 16..26) | pad], 224x32, fp8 frag order
__global__ void k_pack_w1(const float* __restrict__ Wl, const float* __restrict__ Wr,
                          unsigned char* __restrict__ out){
    int lane = threadIdx.x;
    int n  = blockIdx.x * 16 + (lane & 15);
    int k0 = (lane >> 4) * 8;
    float f[8];
    #pragma unroll
    for (int j = 0; j < 8; ++j){
        int k = k0 + j;
        float v = 0.f;
        if (n < 200){
            if (k < 11)                 v = Wl[n * 11 + k];
            else if (k >= 16 && k < 27) v = Wr[n * 11 + (k - 16)];
        }
        f[j] = v;
    }
    uint2 u;
    u.x = pk4_fp8(f[0], f[1], f[2], f[3]);
    u.y = pk4_fp8(f[4], f[5], f[6], f[7]);
    size_t off = ((size_t)blockIdx.x * 64 + lane) * 8;
    *reinterpret_cast<uint2*>(out + off) = u;
}

__global__ void k_pack_b(const float* b0, const float* b1, const float* b2, const float* b3,
                         const float* b4, float* __restrict__ out){
    const float* bs[5] = {b0,b1,b2,b3,b4};
    int l = blockIdx.x, c = threadIdx.x;
    if (c < ROWP) out[l * ROWP + c] = (c < 200) ? bs[l][c] : 0.f;
}

// xp: bf16 rows of 16 (agg11 gather source); xa bytes 16..31: fp8 x half of layer-1 A
__global__ void k_pack_x(const float* __restrict__ x, unsigned short* __restrict__ xp,
                         unsigned char* __restrict__ xa, int N){
    int i = blockIdx.x * blockDim.x + threadIdx.x;
    int node = i >> 4, c = i & 15;
    if (node < N){
        float f = (c < 11) ? x[(size_t)node * 11 + c] : 0.f;
        xp[i] = f2bf(f);
        xa[(size_t)node * 32 + 16 + c] = b1_fp8(f);
    }
}

// ============================ aggregation ============================

// K=11 edge-parallel: half-wave per node; epilogue -> xa bytes 0..15 (fp8 agg)
__global__ __launch_bounds__(256) void k_agg11(
    const unsigned short* __restrict__ xp, const int* __restrict__ row_ptr,
    const int* __restrict__ srcs, const float* __restrict__ inv_deg,
    unsigned char* __restrict__ xa, int N)
{
    int half = threadIdx.x >> 5;              // 0..7
    int node = blockIdx.x * 8 + half;
    int l = threadIdx.x & 31;
    if (node >= N) return;
    int beg = row_ptr[node], end = row_ptr[node + 1];

    float acc[12];
    #pragma unroll
    for (int i = 0; i < 12; ++i) acc[i] = 0.f;

    const uint4* x4 = reinterpret_cast<const uint4*>(xp);
    const uint2* x2 = reinterpret_cast<const uint2*>(xp);
    for (int e = beg + l; e < end; e += 32){
        int sn = srcs[e];
        uint4 a = x4[(size_t)sn * 2];
        uint2 b = x2[(size_t)sn * 4 + 2];
        union { unsigned u; float f; } c;
        c.u = a.x << 16;         acc[0] += c.f;
        c.u = a.x & 0xffff0000u; acc[1] += c.f;
        c.u = a.y << 16;         acc[2] += c.f;
        c.u = a.y & 0xffff0000u; acc[3] += c.f;
        c.u = a.z << 16;         acc[4] += c.f;
        c.u = a.z & 0xffff0000u; acc[5] += c.f;
        c.u = a.w << 16;         acc[6] += c.f;
        c.u = a.w & 0xffff0000u; acc[7] += c.f;
        c.u = b.x << 16;         acc[8] += c.f;
        c.u = b.x & 0xffff0000u; acc[9] += c.f;
        c.u = b.y << 16;         acc[10] += c.f;
        c.u = b.y & 0xffff0000u; acc[11] += c.f;
    }

    #pragma unroll
    for (int i = 0; i < 11; ++i){
        acc[i] += __shfl_xor(acc[i], 1, 64);
        acc[i] += __shfl_xor(acc[i], 2, 64);
        acc[i] += __shfl_xor(acc[i], 4, 64);
        acc[i] += __shfl_xor(acc[i], 8, 64);
        acc[i] += __shfl_xor(acc[i], 16, 64);
    }

    if (l == 0){
        float id = inv_deg[node];
        float v[12];
        #pragma unroll
        for (int i = 0; i < 11; ++i) v[i] = acc[i] * id;
        v[11] = 0.f;
        uint4 o;
        o.x = pk4_fp8(v[0], v[1], v[2], v[3]);
        o.y = pk4_fp8(v[4], v[5], v[6], v[7]);
        o.z = pk4_fp8(v[8], v[9], v[10], v[11]);
        o.w = 0u;
        *reinterpret_cast<uint4*>(xa + (size_t)node * 32) = o;
    }
}

// fp8 gather-aggregate (layers 2..5). One wave per dst node; fp8 agg out.
__device__ __forceinline__ void accum_fp8v(floatx2* a, uint4 u){
    a[0] += __builtin_amdgcn_cvt_pk_f32_fp8((int)u.x, false);
    a[1] += __builtin_amdgcn_cvt_pk_f32_fp8((int)u.x, true );
    a[2] += __builtin_amdgcn_cvt_pk_f32_fp8((int)u.y, false);
    a[3] += __builtin_amdgcn_cvt_pk_f32_fp8((int)u.y, true );
    a[4] += __builtin_amdgcn_cvt_pk_f32_fp8((int)u.z, false);
    a[5] += __builtin_amdgcn_cvt_pk_f32_fp8((int)u.z, true );
    a[6] += __builtin_amdgcn_cvt_pk_f32_fp8((int)u.w, false);
    a[7] += __builtin_amdgcn_cvt_pk_f32_fp8((int)u.w, true );
}

__global__ __launch_bounds__(256) void k_agg200(
    const unsigned char* __restrict__ h8, const int* __restrict__ row_ptr,
    const int* __restrict__ srcs, const float* __restrict__ inv_deg,
    unsigned char* __restrict__ agg, int N)
{
    int node = blockIdx.x * 4 + (threadIdx.x >> 6);
    int lane = threadIdx.x & 63;
    if (node >= N) return;
    int g = lane >> 4;    // group 0..3
    int l = lane & 15;    // lane-in-group; active if l < 14
    int beg = row_ptr[node], end = row_ptr[node + 1];

    floatx2 acc[8];
    #pragma unroll
    for (int i = 0; i < 8; ++i) acc[i] = (floatx2){0.f, 0.f};

    if (l < 14){
        const uint4* h4 = reinterpret_cast<const uint4*>(h8);
        int e = beg + g;
        for (; e + 4 < end; e += 8){
            int sa = srcs[e];
            int sb = srcs[e + 4];
            uint4 ua = h4[(size_t)sa * 14 + l];
            uint4 ub = h4[(size_t)sb * 14 + l];
            accum_fp8v(acc, ua);
            accum_fp8v(acc, ub);
        }
        if (e < end){
            int sa = srcs[e];
            uint4 ua = h4[(size_t)sa * 14 + l];
            accum_fp8v(acc, ua);
        }
    }

    float af[16];
    #pragma unroll
    for (int i = 0; i < 8; ++i){ af[2*i] = acc[i][0]; af[2*i+1] = acc[i][1]; }
    #pragma unroll
    for (int i = 0; i < 16; ++i){
        af[i] += __shfl_xor(af[i], 32, 64);
        af[i] += __shfl_xor(af[i], 16, 64);
    }

    if (g == 0 && l < 14){
        float id = inv_deg[node];
        uint4 o;
        o.x = pk4_fp8(af[0] * id,  af[1] * id,  af[2] * id,  af[3] * id);
        o.y = pk4_fp8(af[4] * id,  af[5] * id,  af[6] * id,  af[7] * id);
        o.z = pk4_fp8(af[8] * id,  af[9] * id,  af[10] * id, af[11] * id);
        o.w = pk4_fp8(af[12] * id, af[13] * id, af[14] * id, af[15] * id);
        *reinterpret_cast<uint4*>(agg + (size_t)node * ROWP + l * 16) = o;
    }
}

// ============================ layer-1 MFMA (fp8, K=32: [agg11 | x11]) ============================

__global__ __launch_bounds__(256) void k_layer1_mfma(
    const unsigned char* __restrict__ xa, const unsigned char* __restrict__ W1p,
    const float* __restrict__ biasp, unsigned char* __restrict__ outp, int M)
{
    const int wave = threadIdx.x >> 6;
    const int lane = threadIdx.x & 63;
    const int n = lane & 15;
    const int q = lane >> 4;
    int row = blockIdx.x * 64 + wave * 16 + n;
    int rowc = row < M ? row : (M - 1);

    long a = *reinterpret_cast<const long*>(xa + (size_t)rowc * 32 + q * 8);

    floatx4 acc[NT];
    #pragma unroll
    for (int nt = 0; nt < NT; ++nt){
        long b = *reinterpret_cast<const long*>(W1p + ((size_t)nt * 64 + lane) * 8);
        acc[nt] = __builtin_amdgcn_mfma_f32_16x16x32_fp8_fp8(a, b, (floatx4){0.f,0.f,0.f,0.f}, 0, 0, 0);
    }

    int r0 = blockIdx.x * 64 + wave * 16 + q * 4;
    #pragma unroll
    for (int nt = 0; nt < NT; ++nt){
        float bsv = biasp[nt * 16 + n];
        #pragma unroll
        for (int r = 0; r < 4; ++r){
            int rr = r0 + r;
            if (rr < M){
                float v = fmaxf(acc[nt][r] + bsv, 0.f);
                outp[(size_t)rr * ROWP + nt * 16 + n] = b1_fp8(v);
            }
        }
    }
}

// ============================ MFMA SAGE GEMM (layers 2..5, fp8) ============================
// r11 structure (64 rows/block, LDS-staged double-buffered B) but fp8 operands:
// half the A/B/write bytes of bf16 at the same MFMA rate & count.
__global__ __launch_bounds__(256) void k_sage_mfma(
    const unsigned char* __restrict__ Aagg, const unsigned char* __restrict__ Ah,
    const unsigned char* __restrict__ Wlp, const unsigned char* __restrict__ Wrp,
    const float* __restrict__ biasp, unsigned char* __restrict__ outp, int M)
{
    __shared__ __align__(16) unsigned char lb[2][NT * 512];   // 2 x 7 KB
    const int wave = threadIdx.x >> 6;
    const int lane = threadIdx.x & 63;
    const int n = lane & 15;
    const int q = lane >> 4;
    int row = blockIdx.x * 64 + wave * 16 + n;
    int rowc = row < M ? row : (M - 1);

    floatx4 acc[NT];
    #pragma unroll
    for (int nt = 0; nt < NT; ++nt) acc[nt] = (floatx4){0.f, 0.f, 0.f, 0.f};

    const unsigned char* Wp[2] = {Wlp, Wrp};
    const unsigned char* Ap[2] = {Aagg, Ah};

    // stage slab 0 (phase 0, ks 0) into buffer 0
    #pragma unroll
    for (int j = 0; j < 4; ++j){
        int c = j * 4 + wave;
        if (c < NT){
            *reinterpret_cast<uint2*>(&lb[0][c * 512 + lane * 8]) =
                *reinterpret_cast<const uint2*>(Wlp + ((size_t)(c * KS) * 64 + lane) * 8);
        }
    }
    __syncthreads();

    int buf = 0;
    #pragma unroll
    for (int phase = 0; phase < 2; ++phase){
        const unsigned char* arow = Ap[phase] + (size_t)rowc * ROWP + q * 8;
        #pragma unroll
        for (int ks = 0; ks < KS; ++ks){
            int ns = phase * KS + ks + 1;
            if (ns < 2 * KS){
                const unsigned char* W = Wp[ns / KS];
                int nks = ns % KS;
                #pragma unroll
                for (int j = 0; j < 4; ++j){
                    int c = j * 4 + wave;
                    if (c < NT){
                        *reinterpret_cast<uint2*>(&lb[buf ^ 1][c * 512 + lane * 8]) =
                            *reinterpret_cast<const uint2*>(W + ((size_t)(c * KS + nks) * 64 + lane) * 8);
                    }
                }
            }
            long a = *reinterpret_cast<const long*>(arow + ks * 32);
            #pragma unroll
            for (int nt = 0; nt < NT; ++nt){
                long b = *reinterpret_cast<const long*>(&lb[buf][nt * 512 + lane * 8]);
                acc[nt] = __builtin_amdgcn_mfma_f32_16x16x32_fp8_fp8(a, b, acc[nt], 0, 0, 0);
            }
            __syncthreads();
            buf ^= 1;
        }
    }

    // epilogue: C/D layout col=lane&15, row=(lane>>4)*4+reg; fp8 h out
    int r0 = blockIdx.x * 64 + wave * 16 + q * 4;
    #pragma unroll
    for (int nt = 0; nt < NT; ++nt){
        float bsv = biasp[nt * 16 + n];
        #pragma unroll
        for (int r = 0; r < 4; ++r){
            int rr = r0 + r;
            if (rr < M){
                float v = fmaxf(acc[nt][r] + bsv, 0.f);
                outp[(size_t)rr * ROWP + nt * 16 + n] = b1_fp8(v);
            }
        }
    }
}

// ============================ pooling (fp8 h in, no shadow write) ============================

__global__ __launch_bounds__(256) void k_pool(
    const unsigned char* __restrict__ h8, const int* __restrict__ gstart,
    float* __restrict__ gsum, int col_off)
{
    int g = blockIdx.x;
    int beg = gstart[g], end = gstart[g+1];
    int len = end - beg;
    if (len <= 0) return;
    int sub = threadIdx.x >> 6;                 // 0..3
    int t   = threadIdx.x & 63;                 // lane
    if (t >= 50) return;                        // 50 x 4 = 200 real cols
    int pidx = blockIdx.y * 4 + sub;            // 0..31
    int chunk = (len + 31) >> 5;
    int rb = beg + pidx * chunk;
    int re = rb + chunk; if (re > end) re = end;
    if (rb >= re) return;
    int c0 = t * 4;

    float s0 = 0.f, s1 = 0.f, s2 = 0.f, s3 = 0.f;
    for (int r = rb; r < re; ++r){
        unsigned u = *reinterpret_cast<const unsigned*>(h8 + (size_t)r * ROWP + c0);
        floatx2 f01 = __builtin_amdgcn_cvt_pk_f32_fp8((int)u, false);
        floatx2 f23 = __builtin_amdgcn_cvt_pk_f32_fp8((int)u, true);
        s0 += f01[0]; s1 += f01[1]; s2 += f23[0]; s3 += f23[1];
    }
    float* gs = &gsum[(size_t)g * 1000 + col_off + c0];
    atomicAdd(gs + 0, s0);
    atomicAdd(gs + 1, s1);
    atomicAdd(gs + 2, s2);
    atomicAdd(gs + 3, s3);
}

__global__ __launch_bounds__(256) void k_pool_finalize(
    float* __restrict__ gsum, const int* __restrict__ gstart, int NG)
{
    int g = blockIdx.x;
    int cnt = gstart[g+1] - gstart[g];
    float inv = 1.0f / fmaxf((float)cnt, 1.0f);
    for (int i = threadIdx.x; i < 1000; i += 256)
        gsum[(size_t)g * 1000 + i] *= inv;
}

// ============================ MLP head (fp32) ============================

__global__ __launch_bounds__(256) void k_mlp(
    const float* __restrict__ in, const float* __restrict__ W,
    const float* __restrict__ b, float* __restrict__ outp, int Fin, int Fout)
{
    __shared__ __align__(16) float row[1000];
    int g = blockIdx.x;
    for (int i = threadIdx.x; i < Fin; i += 256) row[i] = in[(size_t)g * Fin + i];
    __syncthreads();
    int f4 = Fin >> 2;
    for (int c = threadIdx.x; c < Fout; c += 256){
        const float4* w4 = reinterpret_cast<const float4*>(W + (size_t)c * Fin);
        const float4* r4 = reinterpret_cast<const float4*>(row);
        float s = b[c];
        for (int k = 0; k < f4; ++k){
            float4 wv = w4[k]; float4 rv = r4[k];
            s = fmaf(wv.x, rv.x, s);
            s = fmaf(wv.y, rv.y, s);
            s = fmaf(wv.z, rv.z, s);
            s = fmaf(wv.w, rv.w, s);
        }
        outp[(size_t)g * Fout + c] = s;
    }
}

__global__ void k_mlp3(const float* __restrict__ in, const float* __restrict__ W,
                       const float* __restrict__ b, float* __restrict__ outp, int NG)
{
    int g = blockIdx.x * blockDim.x + threadIdx.x;
    if (g < NG){
        float s = b[0];
        const float* r = in + (size_t)g * 250;
        for (int k = 0; k < 250; ++k) s = fmaf(r[k], W[k], s);
        outp[g] = 1.0f / (1.0f + expf(-s));
    }
}

// ============================ launch ============================

extern "C" void kernel_launch(void* const* d_in, const int* in_sizes, int n_in,
                              void* d_out, int out_size, void* d_ws, size_t ws_size,
                              hipStream_t stream)
{
    const float* x    = (const float*)d_in[0];
    const int*   ei   = (const int*)d_in[1];
    const int*   batch= (const int*)d_in[2];
    const float* Wl[5]; const float* bl[5]; const float* Wr[5];
    for (int i = 0; i < 5; ++i){
        Wl[i] = (const float*)d_in[3 + 3*i];
        bl[i] = (const float*)d_in[4 + 3*i];
        Wr[i] = (const float*)d_in[5 + 3*i];
    }
    const float* pw1 = (const float*)d_in[18]; const float* pb1 = (const float*)d_in[19];
    const float* pw2 = (const float*)d_in[20]; const float* pb2 = (const float*)d_in[21];
    const float* pw3 = (const float*)d_in[22]; const float* pb3 = (const float*)d_in[23];
    float* out = (float*)d_out;

    const int N  = in_sizes[2];
    const int E  = in_sizes[1] / 2;
    const int NG = out_size;
    const int* esrc = ei;
    const int* edst = ei + E;
    const int nbuck = (N + 63) >> BSHIFT;          // 1563
    const int nblk  = (E + EPB - 1) / EPB;         // 782

    // ---- workspace carve ----
    char* p = (char*)d_ws;
    auto carve = [&](size_t bytes)->void* {
        void* r = (void*)p;
        p += (bytes + 255) & ~(size_t)255;
        return r;
    };
    int*   deg     = (int*)  carve((size_t)N * 4);
    int*   row_ptr = (int*)  carve(((size_t)N + 1) * 4);
    int*   csum    = (int*)  carve(4096);
    int*   hist    = (int*)  carve((size_t)nblk * nbuck * 4);
    int*   Tb      = (int*)  carve((size_t)nbuck * 4);
    int*   tbase   = (int*)  carve(((size_t)nbuck + 1) * 4);
    float* invdeg  = (float*)carve((size_t)N * 4);
    int*   gstart  = (int*)  carve(((size_t)NG + 1) * 4);
    int*   srcs    = (int*)  carve((size_t)E * 4);
    int2*  pairs   = (int2*) carve((size_t)E * 8);
    unsigned short* xp    = (unsigned short*)carve((size_t)N * 16 * 2);
    unsigned char*  xa    = (unsigned char*) carve((size_t)N * 32);
    unsigned char*  agg8  = (unsigned char*) carve((size_t)N * ROWP);
    unsigned char*  h8A   = (unsigned char*) carve((size_t)N * ROWP);
    unsigned char*  h8B   = (unsigned char*) carve((size_t)N * ROWP);
    unsigned char*  wpack = (unsigned char*) carve((size_t)8 * PACK_BYTES);
    unsigned char*  w1pack= (unsigned char*) carve((size_t)PACK1_BYTES);
    float* biasp   = (float*)carve((size_t)5 * ROWP * 4);
    float* gsum    = (float*)carve((size_t)NG * 1000 * 4);
    float* t1      = (float*)carve((size_t)NG * 500 * 4);
    float* t2      = (float*)carve((size_t)NG * 250 * 4);

    // ---- zero what must be zero ----
    hipMemsetAsync(gsum, 0, (size_t)NG * 1000 * 4, stream);

    // ---- packing ----
    k_pack_w<<<dim3(NT, KS, 8), 64, 0, stream>>>(
        Wl[1], Wr[1], Wl[2], Wr[2], Wl[3], Wr[3], Wl[4], Wr[4], wpack);
    k_pack_w1<<<NT, 64, 0, stream>>>(Wl[0], Wr[0], w1pack);
    k_pack_b<<<5, ROWP, 0, stream>>>(bl[0], bl[1], bl[2], bl[3], bl[4], biasp);
    k_pack_x<<<(N * 16 + 255) / 256, 256, 0, stream>>>(x, xp, xa, N);

    // ---- binned CSR build (no hot global atomics) ----
    k_bin_hist<<<nblk, 256, 0, stream>>>(edst, hist, E, nbuck);
    k_col_scan<<<(nbuck + 63) / 64, 256, 0, stream>>>(hist, Tb, nblk, nbuck);
    k_scan_t<<<1, 256, 0, stream>>>(Tb, tbase, nbuck);
    k_bin_scatter<<<nblk, 256, 0, stream>>>(esrc, edst, hist, tbase, pairs, E, nbuck);
    k_bucket_deg<<<nbuck, 256, 0, stream>>>(pairs, tbase, deg, N);
    int nchunks = (N + 1023) / 1024;
    k_scan_sums<<<nchunks, 256, 0, stream>>>(deg, csum, N);
    k_scan_top<<<1, 64, 0, stream>>>(csum, nchunks);
    k_scan_apply<<<nchunks, 256, 0, stream>>>(deg, csum, row_ptr, N, E);
    k_inv_deg<<<(N + 255) / 256, 256, 0, stream>>>(deg, invdeg, N);
    k_place<<<nbuck, 256, 0, stream>>>(pairs, tbase, row_ptr, srcs, N);

    // ---- graph starts ----
    k_gstart_init<<<(NG + 256) / 256, 256, 0, stream>>>(gstart, N, NG);
    k_gstart_mark<<<(N + 255) / 256, 256, 0, stream>>>(batch, gstart, N);
    k_gstart_fix<<<1, 64, 0, stream>>>(gstart, N, NG);

    // ---- layer 1 (fp8 MFMA over K=32 = [agg11 | x11]) ----
    int gb = (N + 63) / 64;
    k_agg11<<<(N + 7) / 8, 256, 0, stream>>>(xp, row_ptr, srcs, invdeg, xa, N);
    k_layer1_mfma<<<gb, 256, 0, stream>>>(xa, w1pack, biasp, h8A, N);
    k_pool<<<dim3(NG, 8), 256, 0, stream>>>(h8A, gstart, gsum, 0);

    // ---- layers 2..5 (fp8 gather + fp8 MFMA) ----
    unsigned char* hc = h8A; unsigned char* hn = h8B;
    int ab = (N + 3) / 4;
    for (int L = 1; L < 5; ++L){
        k_agg200<<<ab, 256, 0, stream>>>(hc, row_ptr, srcs, invdeg, agg8, N);
        const unsigned char* Wlp = wpack + (size_t)((L-1)*2 + 0) * PACK_BYTES;
        const unsigned char* Wrp = wpack + (size_t)((L-1)*2 + 1) * PACK_BYTES;
        k_sage_mfma<<<gb, 256, 0, stream>>>(agg8, hc, Wlp, Wrp,
                                            biasp + L * ROWP, hn, N);
        k_pool<<<dim3(NG, 8), 256, 0, stream>>>(hn, gstart, gsum, 200 * L);
        unsigned char* t = hc; hc = hn; hn = t;
    }

    // ---- pool finalize + MLP head ----
    k_pool_finalize<<<NG, 256, 0, stream>>>(gsum, gstart, NG);
    k_mlp<<<NG, 256, 0, stream>>>(gsum, pw1, pb1, t1, 1000, 500);
    k_mlp<<<NG, 256, 0, stream>>>(t1, pw2, pb2, t2, 500, 250);
    k_mlp3<<<1, 256, 0, stream>>>(t2, pw3, pb3, out, NG);
}

// Round 13
// 1384.083 us; speedup vs baseline: 1.5967x; 1.0327x over previous
//
#include <hip/hip_runtime.h>
#include <math.h>

typedef __attribute__((ext_vector_type(4))) float floatx4;
typedef __attribute__((ext_vector_type(2))) float floatx2;

#define ROWP 208          // padded row length (fp8 bytes) for h/agg buffers: 13 x 16
#define R4   13           // uint4 per row
#define NT 14             // packed weight col-tiles (layout)
#define NTC 13            // used col-tiles (13 x 16 = 208 cols; 200 real)
#define KS 7              // 7 x 32 = 224 K (200 real + pad)
#define PACK_BYTES (NT*KS*64*8)   // bytes per packed fp8 weight matrix (layers 2..5)
#define PACK1_BYTES (NT*64*8)     // layer-1 packed fp8 weight (K=32)
#define STAGE_BYTES (NTC*KS*64*8) // 46592 B staged per phase in sage
#define BSHIFT 6          // 64 nodes per CSR bucket
#define EPB 4096          // edges per binning block
#define MAXBUCK 1600      // LDS capacity for bucket arrays (>= nbuck=1563)

__device__ __forceinline__ unsigned short f2bf(float f){
    union { float f; unsigned u; } v; v.f = f;
    unsigned r = v.u + 0x7FFF + ((v.u >> 16) & 1);
    return (unsigned short)(r >> 16);
}
__device__ __forceinline__ unsigned pk4_fp8(float a, float b, float c, float d){
    int w = __builtin_amdgcn_cvt_pk_fp8_f32(a, b, 0, false);
    w = __builtin_amdgcn_cvt_pk_fp8_f32(c, d, w, true);
    return (unsigned)w;
}
__device__ __forceinline__ unsigned char b1_fp8(float a){
    int w = __builtin_amdgcn_cvt_pk_fp8_f32(a, a, 0, false);
    return (unsigned char)(w & 0xFF);
}

// ============================ binned CSR build (no hot global atomics) ============================

__global__ __launch_bounds__(256) void k_bin_hist(
    const int* __restrict__ dst, int* __restrict__ hist, int E, int nbuck)
{
    __shared__ int lh[MAXBUCK];
    for (int i = threadIdx.x; i < nbuck; i += 256) lh[i] = 0;
    __syncthreads();
    int base = blockIdx.x * EPB;
    #pragma unroll
    for (int k = 0; k < EPB / 256; ++k){
        int e = base + k * 256 + threadIdx.x;
        if (e < E) atomicAdd(&lh[dst[e] >> BSHIFT], 1);
    }
    __syncthreads();
    for (int i = threadIdx.x; i < nbuck; i += 256)
        hist[(size_t)blockIdx.x * nbuck + i] = lh[i];
}

__global__ __launch_bounds__(256) void k_col_scan(
    int* __restrict__ hist, int* __restrict__ T, int nblk, int nbuck)
{
    __shared__ int part[4][64];
    int w = threadIdx.x >> 6, l = threadIdx.x & 63;
    int b = blockIdx.x * 64 + l;
    int chunk = (nblk + 3) >> 2;
    int j0 = w * chunk, j1 = j0 + chunk; if (j1 > nblk) j1 = nblk;
    int s = 0;
    if (b < nbuck)
        for (int j = j0; j < j1; ++j) s += hist[(size_t)j * nbuck + b];
    part[w][l] = s;
    __syncthreads();
    if (b < nbuck){
        int run = 0;
        for (int w2 = 0; w2 < w; ++w2) run += part[w2][l];
        for (int j = j0; j < j1; ++j){
            int v = hist[(size_t)j * nbuck + b];
            hist[(size_t)j * nbuck + b] = run;
            run += v;
        }
        if (w == 3) T[b] = part[0][l] + part[1][l] + part[2][l] + part[3][l];
    }
}

__global__ __launch_bounds__(256) void k_scan_t(
    const int* __restrict__ T, int* __restrict__ tbase, int nbuck)
{
    __shared__ int ts[256];
    int t = threadIdx.x;
    int v[8]; int s = 0;
    int base = t * 8;
    #pragma unroll
    for (int k = 0; k < 8; ++k){
        int idx = base + k;
        v[k] = (idx < nbuck) ? T[idx] : 0;
        s += v[k];
    }
    ts[t] = s; __syncthreads();
    #pragma unroll
    for (int off = 1; off < 256; off <<= 1){
        int p = (t >= off) ? ts[t - off] : 0;
        __syncthreads();
        ts[t] += p;
        __syncthreads();
    }
    int run = ts[t] - s;
    #pragma unroll
    for (int k = 0; k < 8; ++k){
        int idx = base + k;
        if (idx < nbuck) tbase[idx] = run;
        run += v[k];
    }
    if (t == 255) tbase[nbuck] = ts[255];
}

// pairs packed into 4 B: (dst&63) << 26 | src   (src < 2^26)
__global__ __launch_bounds__(256) void k_bin_scatter(
    const int* __restrict__ src, const int* __restrict__ dst,
    const int* __restrict__ off, const int* __restrict__ tbase,
    unsigned* __restrict__ pairs, int E, int nbuck)
{
    __shared__ int lbase[MAXBUCK];
    __shared__ int lc[MAXBUCK];
    for (int i = threadIdx.x; i < nbuck; i += 256){
        lbase[i] = off[(size_t)blockIdx.x * nbuck + i] + tbase[i];
        lc[i] = 0;
    }
    __syncthreads();
    int base = blockIdx.x * EPB;
    #pragma unroll
    for (int k = 0; k < EPB / 256; ++k){
        int e = base + k * 256 + threadIdx.x;
        if (e < E){
            int d = dst[e];
            int b = d >> BSHIFT;
            int r = atomicAdd(&lc[b], 1);
            pairs[lbase[b] + r] = ((unsigned)(d & 63) << 26) | (unsigned)src[e];
        }
    }
}

__global__ __launch_bounds__(256) void k_bucket_deg(
    const unsigned* __restrict__ pairs, const int* __restrict__ tbase,
    int* __restrict__ deg, int N)
{
    __shared__ int ld[64];
    int b = blockIdx.x;
    if (threadIdx.x < 64) ld[threadIdx.x] = 0;
    __syncthreads();
    int pb = tbase[b], pe = tbase[b + 1];
    for (int e = pb + threadIdx.x; e < pe; e += 256)
        atomicAdd(&ld[pairs[e] >> 26], 1);
    __syncthreads();
    if (threadIdx.x < 64){
        int node = (b << BSHIFT) + threadIdx.x;
        if (node < N) deg[node] = ld[threadIdx.x];
    }
}

__global__ __launch_bounds__(256) void k_place(
    const unsigned* __restrict__ pairs, const int* __restrict__ tbase,
    const int* __restrict__ row_ptr, int* __restrict__ srcs, int N)
{
    __shared__ int lrp[64];
    __shared__ int lcur[64];
    int b = blockIdx.x;
    if (threadIdx.x < 64){
        int node = (b << BSHIFT) + threadIdx.x;
        lrp[threadIdx.x] = (node < N) ? row_ptr[node] : 0;
        lcur[threadIdx.x] = 0;
    }
    __syncthreads();
    int pb = tbase[b], pe = tbase[b + 1];
    for (int e = pb + threadIdx.x; e < pe; e += 256){
        unsigned pr = pairs[e];
        int li = pr >> 26;
        int r = atomicAdd(&lcur[li], 1);
        srcs[lrp[li] + r] = (int)(pr & 0x03FFFFFFu);
    }
}

// ============================ row_ptr scan (over deg) ============================

__global__ void k_scan_sums(const int* __restrict__ deg, int* __restrict__ csum, int N){
    __shared__ int sd[256];
    int base = blockIdx.x * 1024;
    int s = 0;
    for (int i = threadIdx.x; i < 1024; i += 256){
        int idx = base + i;
        s += (idx < N) ? deg[idx] : 0;
    }
    sd[threadIdx.x] = s; __syncthreads();
    for (int off = 128; off > 0; off >>= 1){
        if (threadIdx.x < off) sd[threadIdx.x] += sd[threadIdx.x + off];
        __syncthreads();
    }
    if (threadIdx.x == 0) csum[blockIdx.x] = sd[0];
}

__global__ void k_scan_top(int* __restrict__ csum, int n){
    if (blockIdx.x == 0 && threadIdx.x == 0){
        int run = 0;
        for (int i = 0; i < n; ++i){ int v = csum[i]; csum[i] = run; run += v; }
    }
}

__global__ void k_scan_apply(const int* __restrict__ deg, const int* __restrict__ csum,
                             int* __restrict__ row_ptr, int N, int E){
    __shared__ int ts[256];
    int base = blockIdx.x * 1024 + threadIdx.x * 4;
    int v[4]; int s = 0;
    #pragma unroll
    for (int j = 0; j < 4; ++j){
        int idx = base + j;
        v[j] = (idx < N) ? deg[idx] : 0;
        s += v[j];
    }
    ts[threadIdx.x] = s; __syncthreads();
    #pragma unroll
    for (int off = 1; off < 256; off <<= 1){
        int t = (threadIdx.x >= off) ? ts[threadIdx.x - off] : 0;
        __syncthreads();
        ts[threadIdx.x] += t;
        __syncthreads();
    }
    int excl = ts[threadIdx.x] - s + csum[blockIdx.x];
    #pragma unroll
    for (int j = 0; j < 4; ++j){
        int idx = base + j;
        if (idx < N) row_ptr[idx] = excl;
        excl += v[j];
    }
    if (blockIdx.x == 0 && threadIdx.x == 0) row_ptr[N] = E;
}

__global__ void k_inv_deg(const int* __restrict__ deg, float* __restrict__ inv_deg, int N){
    int i = blockIdx.x * blockDim.x + threadIdx.x;
    if (i < N) inv_deg[i] = 1.0f / fmaxf((float)deg[i], 1.0f);
}

// ============================ graph segment starts ============================

__global__ void k_gstart_init(int* __restrict__ gstart, int N, int NG){
    int g = blockIdx.x * blockDim.x + threadIdx.x;
    if (g <= NG) gstart[g] = N;
}

__global__ void k_gstart_mark(const int* __restrict__ batch, int* __restrict__ gstart, int N){
    int i = blockIdx.x * blockDim.x + threadIdx.x;
    if (i < N){
        int b = batch[i];
        if (i == 0 || batch[i-1] != b) atomicMin(&gstart[b], i);
    }
}

__global__ void k_gstart_fix(int* __restrict__ gstart, int N, int NG){
    if (blockIdx.x == 0 && threadIdx.x == 0){
        for (int g = NG - 1; g >= 0; --g)
            if (gstart[g] == N) gstart[g] = gstart[g+1];
    }
}

// ============================ weight / bias / x packing (fp8) ============================

__global__ void k_pack_w(const float* W0, const float* W1, const float* W2, const float* W3,
                         const float* W4, const float* W5, const float* W6, const float* W7,
                         unsigned char* __restrict__ out){
    const float* Ws[8] = {W0,W1,W2,W3,W4,W5,W6,W7};
    const float* W = Ws[blockIdx.z];
    int lane = threadIdx.x;
    int n  = blockIdx.x * 16 + (lane & 15);
    int k0 = blockIdx.y * 32 + (lane >> 4) * 8;
    float f[8];
    #pragma unroll
    for (int j = 0; j < 8; ++j){
        int k = k0 + j;
        f[j] = (n < 200 && k < 200) ? W[n * 200 + k] : 0.f;
    }
    uint2 u;
    u.x = pk4_fp8(f[0], f[1], f[2], f[3]);
    u.y = pk4_fp8(f[4], f[5], f[6], f[7]);
    size_t off = ((((size_t)blockIdx.z * NT + blockIdx.x) * KS + blockIdx.y) * 64 + lane) * 8;
    *reinterpret_cast<uint2*>(out + off) = u;
}

__global__ void k_pack_w1(const float* __restrict__ Wl, const float* __restrict__ Wr,
                          unsigned char* __restrict__ out){
    int lane = threadIdx.x;
    int n  = blockIdx.x * 16 + (lane & 15);
    int k0 = (lane >> 4) * 8;
    float f[8];
    #pragma unroll
    for (int j = 0; j < 8; ++j){
        int k = k0 + j;
        float v = 0.f;
        if (n < 200){
            if (k < 11)                 v = Wl[n * 11 + k];
            else if (k >= 16 && k < 27) v = Wr[n * 11 + (k - 16)];
        }
        f[j] = v;
    }
    uint2 u;
    u.x = pk4_fp8(f[0], f[1], f[2], f[3]);
    u.y = pk4_fp8(f[4], f[5], f[6], f[7]);
    size_t off = ((size_t)blockIdx.x * 64 + lane) * 8;
    *reinterpret_cast<uint2*>(out + off) = u;
}

__global__ void k_pack_b(const float* b0, const float* b1, const float* b2, const float* b3,
                         const float* b4, float* __restrict__ out){
    const float* bs[5] = {b0,b1,b2,b3,b4};
    int l = blockIdx.x, c = threadIdx.x;
    if (c < ROWP) out[l * ROWP + c] = (c < 200) ? bs[l][c] : 0.f;
}

__global__ void k_pack_x(const float* __restrict__ x, unsigned short* __restrict__ xp,
                         unsigned char* __restrict__ xa, int N){
    int i = blockIdx.x * blockDim.x + threadIdx.x;
    int node = i >> 4, c = i & 15;
    if (node < N){
        float f = (c < 11) ? x[(size_t)node * 11 + c] : 0.f;
        xp[i] = f2bf(f);
        xa[(size_t)node * 32 + 16 + c] = b1_fp8(f);
    }
}

// ============================ aggregation ============================

// K=11 edge-parallel: half-wave per node; epilogue -> xa bytes 0..15 (fp8 agg)
__global__ __launch_bounds__(256) void k_agg11(
    const unsigned short* __restrict__ xp, const int* __restrict__ row_ptr,
    const int* __restrict__ srcs, const float* __restrict__ inv_deg,
    unsigned char* __restrict__ xa, int N)
{
    int half = threadIdx.x >> 5;              // 0..7
    int node = blockIdx.x * 8 + half;
    int l = threadIdx.x & 31;
    if (node >= N) return;
    int beg = row_ptr[node], end = row_ptr[node + 1];

    float acc[12];
    #pragma unroll
    for (int i = 0; i < 12; ++i) acc[i] = 0.f;

    const uint4* x4 = reinterpret_cast<const uint4*>(xp);
    const uint2* x2 = reinterpret_cast<const uint2*>(xp);
    for (int e = beg + l; e < end; e += 32){
        int sn = srcs[e];
        uint4 a = x4[(size_t)sn * 2];
        uint2 b = x2[(size_t)sn * 4 + 2];
        union { unsigned u; float f; } c;
        c.u = a.x << 16;         acc[0] += c.f;
        c.u = a.x & 0xffff0000u; acc[1] += c.f;
        c.u = a.y << 16;         acc[2] += c.f;
        c.u = a.y & 0xffff0000u; acc[3] += c.f;
        c.u = a.z << 16;         acc[4] += c.f;
        c.u = a.z & 0xffff0000u; acc[5] += c.f;
        c.u = a.w << 16;         acc[6] += c.f;
        c.u = a.w & 0xffff0000u; acc[7] += c.f;
        c.u = b.x << 16;         acc[8] += c.f;
        c.u = b.x & 0xffff0000u; acc[9] += c.f;
        c.u = b.y << 16;         acc[10] += c.f;
        c.u = b.y & 0xffff0000u; acc[11] += c.f;
    }

    #pragma unroll
    for (int i = 0; i < 11; ++i){
        acc[i] += __shfl_xor(acc[i], 1, 64);
        acc[i] += __shfl_xor(acc[i], 2, 64);
        acc[i] += __shfl_xor(acc[i], 4, 64);
        acc[i] += __shfl_xor(acc[i], 8, 64);
        acc[i] += __shfl_xor(acc[i], 16, 64);
    }

    if (l == 0){
        float id = inv_deg[node];
        float v[12];
        #pragma unroll
        for (int i = 0; i < 11; ++i) v[i] = acc[i] * id;
        v[11] = 0.f;
        uint4 o;
        o.x = pk4_fp8(v[0], v[1], v[2], v[3]);
        o.y = pk4_fp8(v[4], v[5], v[6], v[7]);
        o.z = pk4_fp8(v[8], v[9], v[10], v[11]);
        o.w = 0u;
        *reinterpret_cast<uint4*>(xa + (size_t)node * 32) = o;
    }
}

// fp8 gather-aggregate (layers 2..5). One wave per dst node; 13 active lanes/group.
__device__ __forceinline__ void accum_fp8v(floatx2* a, uint4 u){
    a[0] += __builtin_amdgcn_cvt_pk_f32_fp8((int)u.x, false);
    a[1] += __builtin_amdgcn_cvt_pk_f32_fp8((int)u.x, true );
    a[2] += __builtin_amdgcn_cvt_pk_f32_fp8((int)u.y, false);
    a[3] += __builtin_amdgcn_cvt_pk_f32_fp8((int)u.y, true );
    a[4] += __builtin_amdgcn_cvt_pk_f32_fp8((int)u.z, false);
    a[5] += __builtin_amdgcn_cvt_pk_f32_fp8((int)u.z, true );
    a[6] += __builtin_amdgcn_cvt_pk_f32_fp8((int)u.w, false);
    a[7] += __builtin_amdgcn_cvt_pk_f32_fp8((int)u.w, true );
}

__global__ __launch_bounds__(256) void k_agg200(
    const unsigned char* __restrict__ h8, const int* __restrict__ row_ptr,
    const int* __restrict__ srcs, const float* __restrict__ inv_deg,
    unsigned char* __restrict__ agg, int N)
{
    int node = blockIdx.x * 4 + (threadIdx.x >> 6);
    int lane = threadIdx.x & 63;
    if (node >= N) return;
    int g = lane >> 4;    // group 0..3
    int l = lane & 15;    // lane-in-group; active if l < 13
    int beg = row_ptr[node], end = row_ptr[node + 1];

    floatx2 acc[8];
    #pragma unroll
    for (int i = 0; i < 8; ++i) acc[i] = (floatx2){0.f, 0.f};

    if (l < R4){
        const uint4* h4 = reinterpret_cast<const uint4*>(h8);
        int e = beg + g;
        for (; e + 4 < end; e += 8){
            int sa = srcs[e];
            int sb = srcs[e + 4];
            uint4 ua = h4[(size_t)sa * R4 + l];
            uint4 ub = h4[(size_t)sb * R4 + l];
            accum_fp8v(acc, ua);
            accum_fp8v(acc, ub);
        }
        if (e < end){
            int sa = srcs[e];
            uint4 ua = h4[(size_t)sa * R4 + l];
            accum_fp8v(acc, ua);
        }
    }

    float af[16];
    #pragma unroll
    for (int i = 0; i < 8; ++i){ af[2*i] = acc[i][0]; af[2*i+1] = acc[i][1]; }
    #pragma unroll
    for (int i = 0; i < 16; ++i){
        af[i] += __shfl_xor(af[i], 32, 64);
        af[i] += __shfl_xor(af[i], 16, 64);
    }

    if (g == 0 && l < R4){
        float id = inv_deg[node];
        uint4 o;
        o.x = pk4_fp8(af[0] * id,  af[1] * id,  af[2] * id,  af[3] * id);
        o.y = pk4_fp8(af[4] * id,  af[5] * id,  af[6] * id,  af[7] * id);
        o.z = pk4_fp8(af[8] * id,  af[9] * id,  af[10] * id, af[11] * id);
        o.w = pk4_fp8(af[12] * id, af[13] * id, af[14] * id, af[15] * id);
        *reinterpret_cast<uint4*>(agg + (size_t)node * ROWP + l * 16) = o;
    }
}

// ============================ layer-1 MFMA (fp8, K=32: [agg11 | x11]) ============================

__global__ __launch_bounds__(256) void k_layer1_mfma(
    const unsigned char* __restrict__ xa, const unsigned char* __restrict__ W1p,
    const float* __restrict__ biasp, unsigned char* __restrict__ outp, int M)
{
    const int wave = threadIdx.x >> 6;
    const int lane = threadIdx.x & 63;
    const int n = lane & 15;
    const int q = lane >> 4;
    int row = blockIdx.x * 64 + wave * 16 + n;
    int rowc = row < M ? row : (M - 1);

    long a = *reinterpret_cast<const long*>(xa + (size_t)rowc * 32 + q * 8);

    floatx4 acc[NTC];
    #pragma unroll
    for (int nt = 0; nt < NTC; ++nt){
        long b = *reinterpret_cast<const long*>(W1p + ((size_t)nt * 64 + lane) * 8);
        acc[nt] = __builtin_amdgcn_mfma_f32_16x16x32_fp8_fp8(a, b, (floatx4){0.f,0.f,0.f,0.f}, 0, 0, 0);
    }

    int r0 = blockIdx.x * 64 + wave * 16 + q * 4;
    #pragma unroll
    for (int nt = 0; nt < NTC; ++nt){
        float bsv = biasp[nt * 16 + n];
        #pragma unroll
        for (int r = 0; r < 4; ++r){
            int rr = r0 + r;
            if (rr < M){
                float v = fmaxf(acc[nt][r] + bsv, 0.f);
                outp[(size_t)rr * ROWP + nt * 16 + n] = b1_fp8(v);
            }
        }
    }
}

// ============================ MFMA SAGE GEMM (layers 2..5, fp8) ============================
// Whole-phase LDS staging: the 13 used col-tiles of one weight matrix (45.5 KB
// fp8) are staged ONCE per phase -> 3 barriers per block total (r11/r12 paid a
// barrier + vmcnt drain per K-step = 14/block, the m97-style stall). A-row
// fragments (7 x 8 B) held in regs across the phase. ks outer / nt inner for
// 13 independent acc chains. Rows are 208 B; the K=224 tail (bytes 208..223)
// is synthesized as zero (quads 2,3 of ks=6), bytes 200..207 are stored zeros.
__global__ __launch_bounds__(256) void k_sage_mfma(
    const unsigned char* __restrict__ Aagg, const unsigned char* __restrict__ Ah,
    const unsigned char* __restrict__ Wlp, const unsigned char* __restrict__ Wrp,
    const float* __restrict__ biasp, unsigned char* __restrict__ outp, int M)
{
    __shared__ __align__(16) unsigned char lw[STAGE_BYTES];   // 45.5 KB
    const int wave = threadIdx.x >> 6;
    const int lane = threadIdx.x & 63;
    const int n = lane & 15;
    const int q = lane >> 4;
    int row = blockIdx.x * 64 + wave * 16 + n;
    int rowc = row < M ? row : (M - 1);

    floatx4 acc[NTC];
    #pragma unroll
    for (int nt = 0; nt < NTC; ++nt) acc[nt] = (floatx4){0.f, 0.f, 0.f, 0.f};

    const unsigned char* Wp[2] = {Wlp, Wrp};
    const unsigned char* Ap[2] = {Aagg, Ah};

    #pragma unroll
    for (int phase = 0; phase < 2; ++phase){
        // stage this phase's 13 col-tiles (nt-major layout -> straight copy)
        if (phase) __syncthreads();   // all waves done reading previous phase
        {
            const uint4* src4 = reinterpret_cast<const uint4*>(Wp[phase]);
            uint4* dst4 = reinterpret_cast<uint4*>(lw);
            for (int i = threadIdx.x; i < STAGE_BYTES / 16; i += 256)
                dst4[i] = src4[i];
        }
        __syncthreads();

        const unsigned char* arow = Ap[phase] + (size_t)rowc * ROWP + q * 8;
        long a[KS];
        #pragma unroll
        for (int ks = 0; ks < 6; ++ks)
            a[ks] = *reinterpret_cast<const long*>(arow + ks * 32);
        a[6] = (q < 2) ? *reinterpret_cast<const long*>(arow + 192) : 0L;

        #pragma unroll
        for (int ks = 0; ks < KS; ++ks){
            #pragma unroll
            for (int nt = 0; nt < NTC; ++nt){
                long b = *reinterpret_cast<const long*>(&lw[((nt * KS + ks) * 64 + lane) * 8]);
                acc[nt] = __builtin_amdgcn_mfma_f32_16x16x32_fp8_fp8(a[ks], b, acc[nt], 0, 0, 0);
            }
        }
    }

    // epilogue: C/D layout col=lane&15, row=(lane>>4)*4+reg; fp8 h out
    int r0 = blockIdx.x * 64 + wave * 16 + q * 4;
    #pragma unroll
    for (int nt = 0; nt < NTC; ++nt){
        float bsv = biasp[nt * 16 + n];
        #pragma unroll
        for (int r = 0; r < 4; ++r){
            int rr = r0 + r;
            if (rr < M){
                float v = fmaxf(acc[nt][r] + bsv, 0.f);
                outp[(size_t)rr * ROWP + nt * 16 + n] = b1_fp8(v);
            }
        }
    }
}

// ============================ pooling (fp8 h in) ============================

__global__ __launch_bounds__(256) void k_pool(
    const unsigned char* __restrict__ h8, const int* __restrict__ gstart,
    float* __restrict__ gsum, int col_off)
{
    int g = blockIdx.x;
    int beg = gstart[g], end = gstart[g+1];
    int len = end - beg;
    if (len <= 0) return;
    int sub = threadIdx.x >> 6;                 // 0..3
    int t   = threadIdx.x & 63;                 // lane
    if (t >= 50) return;                        // 50 x 4 = 200 real cols
    int pidx = blockIdx.y * 4 + sub;            // 0..31
    int chunk = (len + 31) >> 5;
    int rb = beg + pidx * chunk;
    int re = rb + chunk; if (re > end) re = end;
    if (rb >= re) return;
    int c0 = t * 4;

    float s0 = 0.f, s1 = 0.f, s2 = 0.f, s3 = 0.f;
    for (int r = rb; r < re; ++r){
        unsigned u = *reinterpret_cast<const unsigned*>(h8 + (size_t)r * ROWP + c0);
        floatx2 f01 = __builtin_amdgcn_cvt_pk_f32_fp8((int)u, false);
        floatx2 f23 = __builtin_amdgcn_cvt_pk_f32_fp8((int)u, true);
        s0 += f01[0]; s1 += f01[1]; s2 += f23[0]; s3 += f23[1];
    }
    float* gs = &gsum[(size_t)g * 1000 + col_off + c0];
    atomicAdd(gs + 0, s0);
    atomicAdd(gs + 1, s1);
    atomicAdd(gs + 2, s2);
    atomicAdd(gs + 3, s3);
}

__global__ __launch_bounds__(256) void k_pool_finalize(
    float* __restrict__ gsum, const int* __restrict__ gstart, int NG)
{
    int g = blockIdx.x;
    int cnt = gstart[g+1] - gstart[g];
    float inv = 1.0f / fmaxf((float)cnt, 1.0f);
    for (int i = threadIdx.x; i < 1000; i += 256)
        gsum[(size_t)g * 1000 + i] *= inv;
}

// ============================ MLP head (fp32) ============================

__global__ __launch_bounds__(256) void k_mlp(
    const float* __restrict__ in, const float* __restrict__ W,
    const float* __restrict__ b, float* __restrict__ outp, int Fin, int Fout)
{
    __shared__ __align__(16) float row[1000];
    int g = blockIdx.x;
    for (int i = threadIdx.x; i < Fin; i += 256) row[i] = in[(size_t)g * Fin + i];
    __syncthreads();
    int f4 = Fin >> 2;
    for (int c = threadIdx.x; c < Fout; c += 256){
        const float4* w4 = reinterpret_cast<const float4*>(W + (size_t)c * Fin);
        const float4* r4 = reinterpret_cast<const float4*>(row);
        float s = b[c];
        for (int k = 0; k < f4; ++k){
            float4 wv = w4[k]; float4 rv = r4[k];
            s = fmaf(wv.x, rv.x, s);
            s = fmaf(wv.y, rv.y, s);
            s = fmaf(wv.z, rv.z, s);
            s = fmaf(wv.w, rv.w, s);
        }
        outp[(size_t)g * Fout + c] = s;
    }
}

__global__ void k_mlp3(const float* __restrict__ in, const float* __restrict__ W,
                       const float* __restrict__ b, float* __restrict__ outp, int NG)
{
    int g = blockIdx.x * blockDim.x + threadIdx.x;
    if (g < NG){
        float s = b[0];
        const float* r = in + (size_t)g * 250;
        for (int k = 0; k < 250; ++k) s = fmaf(r[k], W[k], s);
        outp[g] = 1.0f / (1.0f + expf(-s));
    }
}

// ============================ launch ============================

extern "C" void kernel_launch(void* const* d_in, const int* in_sizes, int n_in,
                              void* d_out, int out_size, void* d_ws, size_t ws_size,
                              hipStream_t stream)
{
    const float* x    = (const float*)d_in[0];
    const int*   ei   = (const int*)d_in[1];
    const int*   batch= (const int*)d_in[2];
    const float* Wl[5]; const float* bl[5]; const float* Wr[5];
    for (int i = 0; i < 5; ++i){
        Wl[i] = (const float*)d_in[3 + 3*i];
        bl[i] = (const float*)d_in[4 + 3*i];
        Wr[i] = (const float*)d_in[5 + 3*i];
    }
    const float* pw1 = (const float*)d_in[18]; const float* pb1 = (const float*)d_in[19];
    const float* pw2 = (const float*)d_in[20]; const float* pb2 = (const float*)d_in[21];
    const float* pw3 = (const float*)d_in[22]; const float* pb3 = (const float*)d_in[23];
    float* out = (float*)d_out;

    const int N  = in_sizes[2];
    const int E  = in_sizes[1] / 2;
    const int NG = out_size;
    const int* esrc = ei;
    const int* edst = ei + E;
    const int nbuck = (N + 63) >> BSHIFT;          // 1563
    const int nblk  = (E + EPB - 1) / EPB;         // 782

    // ---- workspace carve ----
    char* p = (char*)d_ws;
    auto carve = [&](size_t bytes)->void* {
        void* r = (void*)p;
        p += (bytes + 255) & ~(size_t)255;
        return r;
    };
    int*   deg     = (int*)  carve((size_t)N * 4);
    int*   row_ptr = (int*)  carve(((size_t)N + 1) * 4);
    int*   csum    = (int*)  carve(4096);
    int*   hist    = (int*)  carve((size_t)nblk * nbuck * 4);
    int*   Tb      = (int*)  carve((size_t)nbuck * 4);
    int*   tbase   = (int*)  carve(((size_t)nbuck + 1) * 4);
    float* invdeg  = (float*)carve((size_t)N * 4);
    int*   gstart  = (int*)  carve(((size_t)NG + 1) * 4);
    int*   srcs    = (int*)  carve((size_t)E * 4);
    unsigned* pairs = (unsigned*)carve((size_t)E * 4);
    unsigned short* xp    = (unsigned short*)carve((size_t)N * 16 * 2);
    unsigned char*  xa    = (unsigned char*) carve((size_t)N * 32);
    unsigned char*  agg8  = (unsigned char*) carve((size_t)N * ROWP);
    unsigned char*  h8A   = (unsigned char*) carve((size_t)N * ROWP);
    unsigned char*  h8B   = (unsigned char*) carve((size_t)N * ROWP);
    unsigned char*  wpack = (unsigned char*) carve((size_t)8 * PACK_BYTES);
    unsigned char*  w1pack= (unsigned char*) carve((size_t)PACK1_BYTES);
    float* biasp   = (float*)carve((size_t)5 * ROWP * 4);
    float* gsum    = (float*)carve((size_t)NG * 1000 * 4);
    float* t1      = (float*)carve((size_t)NG * 500 * 4);
    float* t2      = (float*)carve((size_t)NG * 250 * 4);

    // ---- zero what must be zero ----
    hipMemsetAsync(gsum, 0, (size_t)NG * 1000 * 4, stream);

    // ---- packing ----
    k_pack_w<<<dim3(NT, KS, 8), 64, 0, stream>>>(
        Wl[1], Wr[1], Wl[2], Wr[2], Wl[3], Wr[3], Wl[4], Wr[4], wpack);
    k_pack_w1<<<NT, 64, 0, stream>>>(Wl[0], Wr[0], w1pack);
    k_pack_b<<<5, ROWP, 0, stream>>>(bl[0], bl[1], bl[2], bl[3], bl[4], biasp);
    k_pack_x<<<(N * 16 + 255) / 256, 256, 0, stream>>>(x, xp, xa, N);

    // ---- binned CSR build (no hot global atomics) ----
    k_bin_hist<<<nblk, 256, 0, stream>>>(edst, hist, E, nbuck);
    k_col_scan<<<(nbuck + 63) / 64, 256, 0, stream>>>(hist, Tb, nblk, nbuck);
    k_scan_t<<<1, 256, 0, stream>>>(Tb, tbase, nbuck);
    k_bin_scatter<<<nblk, 256, 0, stream>>>(esrc, edst, hist, tbase, pairs, E, nbuck);
    k_bucket_deg<<<nbuck, 256, 0, stream>>>(pairs, tbase, deg, N);
    int nchunks = (N + 1023) / 1024;
    k_scan_sums<<<nchunks, 256, 0, stream>>>(deg, csum, N);
    k_scan_top<<<1, 64, 0, stream>>>(csum, nchunks);
    k_scan_apply<<<nchunks, 256, 0, stream>>>(deg, csum, row_ptr, N, E);
    k_inv_deg<<<(N + 255) / 256, 256, 0, stream>>>(deg, invdeg, N);
    k_place<<<nbuck, 256, 0, stream>>>(pairs, tbase, row_ptr, srcs, N);

    // ---- graph starts ----
    k_gstart_init<<<(NG + 256) / 256, 256, 0, stream>>>(gstart, N, NG);
    k_gstart_mark<<<(N + 255) / 256, 256, 0, stream>>>(batch, gstart, N);
    k_gstart_fix<<<1, 64, 0, stream>>>(gstart, N, NG);

    // ---- layer 1 (fp8 MFMA over K=32 = [agg11 | x11]) ----
    int gb = (N + 63) / 64;
    k_agg11<<<(N + 7) / 8, 256, 0, stream>>>(xp, row_ptr, srcs, invdeg, xa, N);
    k_layer1_mfma<<<gb, 256, 0, stream>>>(xa, w1pack, biasp, h8A, N);
    k_pool<<<dim3(NG, 8), 256, 0, stream>>>(h8A, gstart, gsum, 0);

    // ---- layers 2..5 (fp8 gather + fp8 MFMA) ----
    unsigned char* hc = h8A; unsigned char* hn = h8B;
    int ab = (N + 3) / 4;
    for (int L = 1; L < 5; ++L){
        k_agg200<<<ab, 256, 0, stream>>>(hc, row_ptr, srcs, invdeg, agg8, N);
        const unsigned char* Wlp = wpack + (size_t)((L-1)*2 + 0) * PACK_BYTES;
        const unsigned char* Wrp = wpack + (size_t)((L-1)*2 + 1) * PACK_BYTES;
        k_sage_mfma<<<gb, 256, 0, stream>>>(agg8, hc, Wlp, Wrp,
                                            biasp + L * ROWP, hn, N);
        k_pool<<<dim3(NG, 8), 256, 0, stream>>>(hn, gstart, gsum, 200 * L);
        unsigned char* t = hc; hc = hn; hn = t;
    }

    // ---- pool finalize + MLP head ----
    k_pool_finalize<<<NG, 256, 0, stream>>>(gsum, gstart, NG);
    k_mlp<<<NG, 256, 0, stream>>>(gsum, pw1, pb1, t1, 1000, 500);
    k_mlp<<<NG, 256, 0, stream>>>(t1, pw2, pb2, t2, 500, 250);
    k_mlp3<<<1, 256, 0, stream>>>(t2, pw3, pb3, out, NG);
}

// Round 14
// 1294.595 us; speedup vs baseline: 1.7071x; 1.0691x over previous
//
#include <hip/hip_runtime.h>
#include <math.h>

typedef __attribute__((ext_vector_type(4))) float floatx4;
typedef __attribute__((ext_vector_type(2))) float floatx2;

#define ROWP 208          // padded row length (fp8 bytes) for h/agg buffers: 13 x 16
#define R4   13           // uint4 per row
#define NT 14             // packed weight col-tiles (layout)
#define NTC 13            // used col-tiles (13 x 16 = 208 cols; 200 real)
#define KS 7              // 7 x 32 = 224 K (200 real + pad)
#define PACK_BYTES (NT*KS*64*8)   // bytes per packed fp8 weight matrix (layers 2..5)
#define PACK1_BYTES (NT*64*8)     // layer-1 packed fp8 weight (K=32)
#define STAGE_BYTES (NTC*KS*64*8) // 46592 B staged per phase in sage
#define BSHIFT 6          // 64 nodes per CSR bucket
#define EPB 4096          // edges per binning block
#define MAXBUCK 1600      // LDS capacity for bucket arrays (>= nbuck=1563)

__device__ __forceinline__ unsigned short f2bf(float f){
    union { float f; unsigned u; } v; v.f = f;
    unsigned r = v.u + 0x7FFF + ((v.u >> 16) & 1);
    return (unsigned short)(r >> 16);
}
__device__ __forceinline__ unsigned pk4_fp8(float a, float b, float c, float d){
    int w = __builtin_amdgcn_cvt_pk_fp8_f32(a, b, 0, false);
    w = __builtin_amdgcn_cvt_pk_fp8_f32(c, d, w, true);
    return (unsigned)w;
}
__device__ __forceinline__ unsigned char b1_fp8(float a){
    int w = __builtin_amdgcn_cvt_pk_fp8_f32(a, a, 0, false);
    return (unsigned char)(w & 0xFF);
}

// ============================ binned CSR build (no hot global atomics) ============================

__global__ __launch_bounds__(256) void k_bin_hist(
    const int* __restrict__ dst, int* __restrict__ hist, int E, int nbuck)
{
    __shared__ int lh[MAXBUCK];
    for (int i = threadIdx.x; i < nbuck; i += 256) lh[i] = 0;
    __syncthreads();
    int base = blockIdx.x * EPB;
    #pragma unroll
    for (int k = 0; k < EPB / 256; ++k){
        int e = base + k * 256 + threadIdx.x;
        if (e < E) atomicAdd(&lh[dst[e] >> BSHIFT], 1);
    }
    __syncthreads();
    for (int i = threadIdx.x; i < nbuck; i += 256)
        hist[(size_t)blockIdx.x * nbuck + i] = lh[i];
}

__global__ __launch_bounds__(256) void k_col_scan(
    int* __restrict__ hist, int* __restrict__ T, int nblk, int nbuck)
{
    __shared__ int part[4][64];
    int w = threadIdx.x >> 6, l = threadIdx.x & 63;
    int b = blockIdx.x * 64 + l;
    int chunk = (nblk + 3) >> 2;
    int j0 = w * chunk, j1 = j0 + chunk; if (j1 > nblk) j1 = nblk;
    int s = 0;
    if (b < nbuck)
        for (int j = j0; j < j1; ++j) s += hist[(size_t)j * nbuck + b];
    part[w][l] = s;
    __syncthreads();
    if (b < nbuck){
        int run = 0;
        for (int w2 = 0; w2 < w; ++w2) run += part[w2][l];
        for (int j = j0; j < j1; ++j){
            int v = hist[(size_t)j * nbuck + b];
            hist[(size_t)j * nbuck + b] = run;
            run += v;
        }
        if (w == 3) T[b] = part[0][l] + part[1][l] + part[2][l] + part[3][l];
    }
}

__global__ __launch_bounds__(256) void k_scan_t(
    const int* __restrict__ T, int* __restrict__ tbase, int nbuck)
{
    __shared__ int ts[256];
    int t = threadIdx.x;
    int v[8]; int s = 0;
    int base = t * 8;
    #pragma unroll
    for (int k = 0; k < 8; ++k){
        int idx = base + k;
        v[k] = (idx < nbuck) ? T[idx] : 0;
        s += v[k];
    }
    ts[t] = s; __syncthreads();
    #pragma unroll
    for (int off = 1; off < 256; off <<= 1){
        int p = (t >= off) ? ts[t - off] : 0;
        __syncthreads();
        ts[t] += p;
        __syncthreads();
    }
    int run = ts[t] - s;
    #pragma unroll
    for (int k = 0; k < 8; ++k){
        int idx = base + k;
        if (idx < nbuck) tbase[idx] = run;
        run += v[k];
    }
    if (t == 255) tbase[nbuck] = ts[255];
}

// pairs packed into 4 B: (dst&63) << 26 | src   (src < 2^26)
__global__ __launch_bounds__(256) void k_bin_scatter(
    const int* __restrict__ src, const int* __restrict__ dst,
    const int* __restrict__ off, const int* __restrict__ tbase,
    unsigned* __restrict__ pairs, int E, int nbuck)
{
    __shared__ int lbase[MAXBUCK];
    __shared__ int lc[MAXBUCK];
    for (int i = threadIdx.x; i < nbuck; i += 256){
        lbase[i] = off[(size_t)blockIdx.x * nbuck + i] + tbase[i];
        lc[i] = 0;
    }
    __syncthreads();
    int base = blockIdx.x * EPB;
    #pragma unroll
    for (int k = 0; k < EPB / 256; ++k){
        int e = base + k * 256 + threadIdx.x;
        if (e < E){
            int d = dst[e];
            int b = d >> BSHIFT;
            int r = atomicAdd(&lc[b], 1);
            pairs[lbase[b] + r] = ((unsigned)(d & 63) << 26) | (unsigned)src[e];
        }
    }
}

// bucket degree count + inv_deg (fused)
__global__ __launch_bounds__(256) void k_bucket_deg(
    const unsigned* __restrict__ pairs, const int* __restrict__ tbase,
    int* __restrict__ deg, float* __restrict__ inv_deg, int N)
{
    __shared__ int ld[64];
    int b = blockIdx.x;
    if (threadIdx.x < 64) ld[threadIdx.x] = 0;
    __syncthreads();
    int pb = tbase[b], pe = tbase[b + 1];
    for (int e = pb + threadIdx.x; e < pe; e += 256)
        atomicAdd(&ld[pairs[e] >> 26], 1);
    __syncthreads();
    if (threadIdx.x < 64){
        int node = (b << BSHIFT) + threadIdx.x;
        if (node < N){
            int d = ld[threadIdx.x];
            deg[node] = d;
            inv_deg[node] = 1.0f / fmaxf((float)d, 1.0f);
        }
    }
}

__global__ __launch_bounds__(256) void k_place(
    const unsigned* __restrict__ pairs, const int* __restrict__ tbase,
    const int* __restrict__ row_ptr, int* __restrict__ srcs, int N)
{
    __shared__ int lrp[64];
    __shared__ int lcur[64];
    int b = blockIdx.x;
    if (threadIdx.x < 64){
        int node = (b << BSHIFT) + threadIdx.x;
        lrp[threadIdx.x] = (node < N) ? row_ptr[node] : 0;
        lcur[threadIdx.x] = 0;
    }
    __syncthreads();
    int pb = tbase[b], pe = tbase[b + 1];
    for (int e = pb + threadIdx.x; e < pe; e += 256){
        unsigned pr = pairs[e];
        int li = pr >> 26;
        int r = atomicAdd(&lcur[li], 1);
        srcs[lrp[li] + r] = (int)(pr & 0x03FFFFFFu);
    }
}

// ============================ row_ptr scan (over deg) ============================

__global__ void k_scan_sums(const int* __restrict__ deg, int* __restrict__ csum, int N){
    __shared__ int sd[256];
    int base = blockIdx.x * 1024;
    int s = 0;
    for (int i = threadIdx.x; i < 1024; i += 256){
        int idx = base + i;
        s += (idx < N) ? deg[idx] : 0;
    }
    sd[threadIdx.x] = s; __syncthreads();
    for (int off = 128; off > 0; off >>= 1){
        if (threadIdx.x < off) sd[threadIdx.x] += sd[threadIdx.x + off];
        __syncthreads();
    }
    if (threadIdx.x == 0) csum[blockIdx.x] = sd[0];
}

// scan_apply with built-in top-scan: csum holds RAW per-chunk sums; each block
// reduces csum[j<bid] itself (nchunks ~98, trivial) -> no separate k_scan_top.
__global__ void k_scan_apply(const int* __restrict__ deg, const int* __restrict__ csum,
                             int* __restrict__ row_ptr, int N, int E, int nchunks){
    __shared__ int ts[256];
    __shared__ int base_s;
    int partial = 0;
    for (int j = threadIdx.x; j < nchunks; j += 256)
        if (j < (int)blockIdx.x) partial += csum[j];
    ts[threadIdx.x] = partial; __syncthreads();
    for (int off = 128; off > 0; off >>= 1){
        if (threadIdx.x < off) ts[threadIdx.x] += ts[threadIdx.x + off];
        __syncthreads();
    }
    if (threadIdx.x == 0) base_s = ts[0];
    __syncthreads();
    int blk_base = base_s;
    __syncthreads();   // everyone read base_s; ts about to be reused

    int base = blockIdx.x * 1024 + threadIdx.x * 4;
    int v[4]; int s = 0;
    #pragma unroll
    for (int j = 0; j < 4; ++j){
        int idx = base + j;
        v[j] = (idx < N) ? deg[idx] : 0;
        s += v[j];
    }
    ts[threadIdx.x] = s; __syncthreads();
    #pragma unroll
    for (int off = 1; off < 256; off <<= 1){
        int t = (threadIdx.x >= off) ? ts[threadIdx.x - off] : 0;
        __syncthreads();
        ts[threadIdx.x] += t;
        __syncthreads();
    }
    int excl = ts[threadIdx.x] - s + blk_base;
    #pragma unroll
    for (int j = 0; j < 4; ++j){
        int idx = base + j;
        if (idx < N) row_ptr[idx] = excl;
        excl += v[j];
    }
    if (blockIdx.x == 0 && threadIdx.x == 0) row_ptr[N] = E;
}

// ============================ graph segment starts (binary search) ============================
// batch sorted ascending: gstart[g] = lower_bound(batch, g); empty graphs
// naturally get the next present graph's start. gstart[NG] = N.
__global__ void k_gstart_bs(const int* __restrict__ batch, int* __restrict__ gstart,
                            int N, int NG){
    int g = blockIdx.x * blockDim.x + threadIdx.x;
    if (g > NG) return;
    int lo = 0, hi = N;
    while (lo < hi){
        int mid = (lo + hi) >> 1;
        if (batch[mid] < g) lo = mid + 1; else hi = mid;
    }
    gstart[g] = lo;
}

// ============================ packing (fp8) ============================

__global__ void k_pack_w(const float* W0, const float* W1, const float* W2, const float* W3,
                         const float* W4, const float* W5, const float* W6, const float* W7,
                         unsigned char* __restrict__ out){
    const float* Ws[8] = {W0,W1,W2,W3,W4,W5,W6,W7};
    const float* W = Ws[blockIdx.z];
    int lane = threadIdx.x;
    int n  = blockIdx.x * 16 + (lane & 15);
    int k0 = blockIdx.y * 32 + (lane >> 4) * 8;
    float f[8];
    #pragma unroll
    for (int j = 0; j < 8; ++j){
        int k = k0 + j;
        f[j] = (n < 200 && k < 200) ? W[n * 200 + k] : 0.f;
    }
    uint2 u;
    u.x = pk4_fp8(f[0], f[1], f[2], f[3]);
    u.y = pk4_fp8(f[4], f[5], f[6], f[7]);
    size_t off = ((((size_t)blockIdx.z * NT + blockIdx.x) * KS + blockIdx.y) * 64 + lane) * 8;
    *reinterpret_cast<uint2*>(out + off) = u;
}

// combined: pack_x (blocks 0..xblk-1), pack_w1 (next NT blocks), pack_b (next 5)
__global__ __launch_bounds__(256) void k_pack_misc(
    const float* __restrict__ x, unsigned short* __restrict__ xp,
    unsigned char* __restrict__ xa,
    const float* __restrict__ Wl1, const float* __restrict__ Wr1,
    unsigned char* __restrict__ w1pack,
    const float* b0, const float* b1, const float* b2, const float* b3, const float* b4,
    float* __restrict__ biasp, int N, int xblk)
{
    int bid = blockIdx.x;
    if (bid < xblk){
        int i = bid * 256 + threadIdx.x;
        int node = i >> 4, c = i & 15;
        if (node < N){
            float f = (c < 11) ? x[(size_t)node * 11 + c] : 0.f;
            xp[i] = f2bf(f);
            xa[(size_t)node * 32 + 16 + c] = b1_fp8(f);
        }
        return;
    }
    int j = bid - xblk;
    if (j < NT){
        if (threadIdx.x >= 64) return;
        int lane = threadIdx.x;
        int n  = j * 16 + (lane & 15);
        int k0 = (lane >> 4) * 8;
        float f[8];
        #pragma unroll
        for (int jj = 0; jj < 8; ++jj){
            int k = k0 + jj;
            float v = 0.f;
            if (n < 200){
                if (k < 11)                 v = Wl1[n * 11 + k];
                else if (k >= 16 && k < 27) v = Wr1[n * 11 + (k - 16)];
            }
            f[jj] = v;
        }
        uint2 u;
        u.x = pk4_fp8(f[0], f[1], f[2], f[3]);
        u.y = pk4_fp8(f[4], f[5], f[6], f[7]);
        size_t off = ((size_t)j * 64 + lane) * 8;
        *reinterpret_cast<uint2*>(w1pack + off) = u;
        return;
    }
    int l = j - NT;   // 0..4
    const float* bs[5] = {b0,b1,b2,b3,b4};
    int c = threadIdx.x;
    if (c < ROWP) biasp[l * ROWP + c] = (c < 200) ? bs[l][c] : 0.f;
}

// ============================ aggregation ============================

// K=11 edge-parallel: half-wave per node; epilogue -> xa bytes 0..15 (fp8 agg)
__global__ __launch_bounds__(256) void k_agg11(
    const unsigned short* __restrict__ xp, const int* __restrict__ row_ptr,
    const int* __restrict__ srcs, const float* __restrict__ inv_deg,
    unsigned char* __restrict__ xa, int N)
{
    int half = threadIdx.x >> 5;              // 0..7
    int node = blockIdx.x * 8 + half;
    int l = threadIdx.x & 31;
    if (node >= N) return;
    int beg = row_ptr[node], end = row_ptr[node + 1];

    float acc[12];
    #pragma unroll
    for (int i = 0; i < 12; ++i) acc[i] = 0.f;

    const uint4* x4 = reinterpret_cast<const uint4*>(xp);
    const uint2* x2 = reinterpret_cast<const uint2*>(xp);
    for (int e = beg + l; e < end; e += 32){
        int sn = srcs[e];
        uint4 a = x4[(size_t)sn * 2];
        uint2 b = x2[(size_t)sn * 4 + 2];
        union { unsigned u; float f; } c;
        c.u = a.x << 16;         acc[0] += c.f;
        c.u = a.x & 0xffff0000u; acc[1] += c.f;
        c.u = a.y << 16;         acc[2] += c.f;
        c.u = a.y & 0xffff0000u; acc[3] += c.f;
        c.u = a.z << 16;         acc[4] += c.f;
        c.u = a.z & 0xffff0000u; acc[5] += c.f;
        c.u = a.w << 16;         acc[6] += c.f;
        c.u = a.w & 0xffff0000u; acc[7] += c.f;
        c.u = b.x << 16;         acc[8] += c.f;
        c.u = b.x & 0xffff0000u; acc[9] += c.f;
        c.u = b.y << 16;         acc[10] += c.f;
        c.u = b.y & 0xffff0000u; acc[11] += c.f;
    }

    #pragma unroll
    for (int i = 0; i < 11; ++i){
        acc[i] += __shfl_xor(acc[i], 1, 64);
        acc[i] += __shfl_xor(acc[i], 2, 64);
        acc[i] += __shfl_xor(acc[i], 4, 64);
        acc[i] += __shfl_xor(acc[i], 8, 64);
        acc[i] += __shfl_xor(acc[i], 16, 64);
    }

    if (l == 0){
        float id = inv_deg[node];
        float v[12];
        #pragma unroll
        for (int i = 0; i < 11; ++i) v[i] = acc[i] * id;
        v[11] = 0.f;
        uint4 o;
        o.x = pk4_fp8(v[0], v[1], v[2], v[3]);
        o.y = pk4_fp8(v[4], v[5], v[6], v[7]);
        o.z = pk4_fp8(v[8], v[9], v[10], v[11]);
        o.w = 0u;
        *reinterpret_cast<uint4*>(xa + (size_t)node * 32) = o;
    }
}

// fp8 gather-aggregate (layers 2..5). One wave per dst node; 13 active lanes/group.
__device__ __forceinline__ void accum_fp8v(floatx2* a, uint4 u){
    a[0] += __builtin_amdgcn_cvt_pk_f32_fp8((int)u.x, false);
    a[1] += __builtin_amdgcn_cvt_pk_f32_fp8((int)u.x, true );
    a[2] += __builtin_amdgcn_cvt_pk_f32_fp8((int)u.y, false);
    a[3] += __builtin_amdgcn_cvt_pk_f32_fp8((int)u.y, true );
    a[4] += __builtin_amdgcn_cvt_pk_f32_fp8((int)u.z, false);
    a[5] += __builtin_amdgcn_cvt_pk_f32_fp8((int)u.z, true );
    a[6] += __builtin_amdgcn_cvt_pk_f32_fp8((int)u.w, false);
    a[7] += __builtin_amdgcn_cvt_pk_f32_fp8((int)u.w, true );
}

__global__ __launch_bounds__(256) void k_agg200(
    const unsigned char* __restrict__ h8, const int* __restrict__ row_ptr,
    const int* __restrict__ srcs, const float* __restrict__ inv_deg,
    unsigned char* __restrict__ agg, int N)
{
    int node = blockIdx.x * 4 + (threadIdx.x >> 6);
    int lane = threadIdx.x & 63;
    if (node >= N) return;
    int g = lane >> 4;    // group 0..3
    int l = lane & 15;    // lane-in-group; active if l < 13
    int beg = row_ptr[node], end = row_ptr[node + 1];

    floatx2 acc[8];
    #pragma unroll
    for (int i = 0; i < 8; ++i) acc[i] = (floatx2){0.f, 0.f};

    if (l < R4){
        const uint4* h4 = reinterpret_cast<const uint4*>(h8);
        int e = beg + g;
        for (; e + 4 < end; e += 8){
            int sa = srcs[e];
            int sb = srcs[e + 4];
            uint4 ua = h4[(size_t)sa * R4 + l];
            uint4 ub = h4[(size_t)sb * R4 + l];
            accum_fp8v(acc, ua);
            accum_fp8v(acc, ub);
        }
        if (e < end){
            int sa = srcs[e];
            uint4 ua = h4[(size_t)sa * R4 + l];
            accum_fp8v(acc, ua);
        }
    }

    float af[16];
    #pragma unroll
    for (int i = 0; i < 8; ++i){ af[2*i] = acc[i][0]; af[2*i+1] = acc[i][1]; }
    #pragma unroll
    for (int i = 0; i < 16; ++i){
        af[i] += __shfl_xor(af[i], 32, 64);
        af[i] += __shfl_xor(af[i], 16, 64);
    }

    if (g == 0 && l < R4){
        float id = inv_deg[node];
        uint4 o;
        o.x = pk4_fp8(af[0] * id,  af[1] * id,  af[2] * id,  af[3] * id);
        o.y = pk4_fp8(af[4] * id,  af[5] * id,  af[6] * id,  af[7] * id);
        o.z = pk4_fp8(af[8] * id,  af[9] * id,  af[10] * id, af[11] * id);
        o.w = pk4_fp8(af[12] * id, af[13] * id, af[14] * id, af[15] * id);
        *reinterpret_cast<uint4*>(agg + (size_t)node * ROWP + l * 16) = o;
    }
}

// ============================ layer-1 MFMA (fp8, K=32: [agg11 | x11]) ============================

__global__ __launch_bounds__(256) void k_layer1_mfma(
    const unsigned char* __restrict__ xa, const unsigned char* __restrict__ W1p,
    const float* __restrict__ biasp, unsigned char* __restrict__ outp, int M)
{
    const int wave = threadIdx.x >> 6;
    const int lane = threadIdx.x & 63;
    const int n = lane & 15;
    const int q = lane >> 4;
    int row = blockIdx.x * 64 + wave * 16 + n;
    int rowc = row < M ? row : (M - 1);

    long a = *reinterpret_cast<const long*>(xa + (size_t)rowc * 32 + q * 8);

    floatx4 acc[NTC];
    #pragma unroll
    for (int nt = 0; nt < NTC; ++nt){
        long b = *reinterpret_cast<const long*>(W1p + ((size_t)nt * 64 + lane) * 8);
        acc[nt] = __builtin_amdgcn_mfma_f32_16x16x32_fp8_fp8(a, b, (floatx4){0.f,0.f,0.f,0.f}, 0, 0, 0);
    }

    int r0 = blockIdx.x * 64 + wave * 16 + q * 4;
    #pragma unroll
    for (int nt = 0; nt < NTC; ++nt){
        float bsv = biasp[nt * 16 + n];
        #pragma unroll
        for (int r = 0; r < 4; ++r){
            int rr = r0 + r;
            if (rr < M){
                float v = fmaxf(acc[nt][r] + bsv, 0.f);
                outp[(size_t)rr * ROWP + nt * 16 + n] = b1_fp8(v);
            }
        }
    }
}

// ============================ MFMA SAGE GEMM (layers 2..5, fp8) ============================
// Whole-phase LDS staging (45.5 KB): 3 barriers per block total.
__global__ __launch_bounds__(256) void k_sage_mfma(
    const unsigned char* __restrict__ Aagg, const unsigned char* __restrict__ Ah,
    const unsigned char* __restrict__ Wlp, const unsigned char* __restrict__ Wrp,
    const float* __restrict__ biasp, unsigned char* __restrict__ outp, int M)
{
    __shared__ __align__(16) unsigned char lw[STAGE_BYTES];   // 45.5 KB
    const int wave = threadIdx.x >> 6;
    const int lane = threadIdx.x & 63;
    const int n = lane & 15;
    const int q = lane >> 4;
    int row = blockIdx.x * 64 + wave * 16 + n;
    int rowc = row < M ? row : (M - 1);

    floatx4 acc[NTC];
    #pragma unroll
    for (int nt = 0; nt < NTC; ++nt) acc[nt] = (floatx4){0.f, 0.f, 0.f, 0.f};

    const unsigned char* Wp[2] = {Wlp, Wrp};
    const unsigned char* Ap[2] = {Aagg, Ah};

    #pragma unroll
    for (int phase = 0; phase < 2; ++phase){
        if (phase) __syncthreads();   // all waves done reading previous phase
        {
            const uint4* src4 = reinterpret_cast<const uint4*>(Wp[phase]);
            uint4* dst4 = reinterpret_cast<uint4*>(lw);
            for (int i = threadIdx.x; i < STAGE_BYTES / 16; i += 256)
                dst4[i] = src4[i];
        }
        __syncthreads();

        const unsigned char* arow = Ap[phase] + (size_t)rowc * ROWP + q * 8;
        long a[KS];
        #pragma unroll
        for (int ks = 0; ks < 6; ++ks)
            a[ks] = *reinterpret_cast<const long*>(arow + ks * 32);
        a[6] = (q < 2) ? *reinterpret_cast<const long*>(arow + 192) : 0L;

        #pragma unroll
        for (int ks = 0; ks < KS; ++ks){
            #pragma unroll
            for (int nt = 0; nt < NTC; ++nt){
                long b = *reinterpret_cast<const long*>(&lw[((nt * KS + ks) * 64 + lane) * 8]);
                acc[nt] = __builtin_amdgcn_mfma_f32_16x16x32_fp8_fp8(a[ks], b, acc[nt], 0, 0, 0);
            }
        }
    }

    int r0 = blockIdx.x * 64 + wave * 16 + q * 4;
    #pragma unroll
    for (int nt = 0; nt < NTC; ++nt){
        float bsv = biasp[nt * 16 + n];
        #pragma unroll
        for (int r = 0; r < 4; ++r){
            int rr = r0 + r;
            if (rr < M){
                float v = fmaxf(acc[nt][r] + bsv, 0.f);
                outp[(size_t)rr * ROWP + nt * 16 + n] = b1_fp8(v);
            }
        }
    }
}

// ============================ pooling (fp8 h in) ============================

__global__ __launch_bounds__(256) void k_pool(
    const unsigned char* __restrict__ h8, const int* __restrict__ gstart,
    float* __restrict__ gsum, int col_off)
{
    int g = blockIdx.x;
    int beg = gstart[g], end = gstart[g+1];
    int len = end - beg;
    if (len <= 0) return;
    int sub = threadIdx.x >> 6;                 // 0..3
    int t   = threadIdx.x & 63;                 // lane
    if (t >= 50) return;                        // 50 x 4 = 200 real cols
    int pidx = blockIdx.y * 4 + sub;            // 0..31
    int chunk = (len + 31) >> 5;
    int rb = beg + pidx * chunk;
    int re = rb + chunk; if (re > end) re = end;
    if (rb >= re) return;
    int c0 = t * 4;

    float s0 = 0.f, s1 = 0.f, s2 = 0.f, s3 = 0.f;
    for (int r = rb; r < re; ++r){
        unsigned u = *reinterpret_cast<const unsigned*>(h8 + (size_t)r * ROWP + c0);
        floatx2 f01 = __builtin_amdgcn_cvt_pk_f32_fp8((int)u, false);
        floatx2 f23 = __builtin_amdgcn_cvt_pk_f32_fp8((int)u, true);
        s0 += f01[0]; s1 += f01[1]; s2 += f23[0]; s3 += f23[1];
    }
    float* gs = &gsum[(size_t)g * 1000 + col_off + c0];
    atomicAdd(gs + 0, s0);
    atomicAdd(gs + 1, s1);
    atomicAdd(gs + 2, s2);
    atomicAdd(gs + 3, s3);
}

// ============================ MLP head (fp32) ============================

// layer 1 of head (1000 -> 500) with pooling finalize fused (scale by 1/cnt)
__global__ __launch_bounds__(256) void k_mlp_first(
    const float* __restrict__ gsum, const int* __restrict__ gstart,
    const float* __restrict__ W, const float* __restrict__ b,
    float* __restrict__ outp)
{
    __shared__ __align__(16) float row[1000];
    int g = blockIdx.x;
    int cnt = gstart[g+1] - gstart[g];
    float inv = 1.0f / fmaxf((float)cnt, 1.0f);
    for (int i = threadIdx.x; i < 1000; i += 256)
        row[i] = gsum[(size_t)g * 1000 + i] * inv;
    __syncthreads();
    for (int c = threadIdx.x; c < 500; c += 256){
        const float4* w4 = reinterpret_cast<const float4*>(W + (size_t)c * 1000);
        const float4* r4 = reinterpret_cast<const float4*>(row);
        float s = b[c];
        for (int k = 0; k < 250; ++k){
            float4 wv = w4[k]; float4 rv = r4[k];
            s = fmaf(wv.x, rv.x, s);
            s = fmaf(wv.y, rv.y, s);
            s = fmaf(wv.z, rv.z, s);
            s = fmaf(wv.w, rv.w, s);
        }
        outp[(size_t)g * 500 + c] = s;
    }
}

// layers 2+3 of head fused: (500 -> 250) -> dot(250) -> sigmoid
__global__ __launch_bounds__(256) void k_mlp23(
    const float* __restrict__ t1, const float* __restrict__ W2,
    const float* __restrict__ b2, const float* __restrict__ W3,
    const float* __restrict__ b3, float* __restrict__ outp)
{
    __shared__ __align__(16) float row[500];
    __shared__ float red[256];
    int g = blockIdx.x;
    for (int i = threadIdx.x; i < 500; i += 256) row[i] = t1[(size_t)g * 500 + i];
    __syncthreads();
    float prod = 0.f;
    int c = threadIdx.x;
    if (c < 250){
        const float4* w4 = reinterpret_cast<const float4*>(W2 + (size_t)c * 500);
        const float4* r4 = reinterpret_cast<const float4*>(row);
        float s = b2[c];
        for (int k = 0; k < 125; ++k){
            float4 wv = w4[k]; float4 rv = r4[k];
            s = fmaf(wv.x, rv.x, s);
            s = fmaf(wv.y, rv.y, s);
            s = fmaf(wv.z, rv.z, s);
            s = fmaf(wv.w, rv.w, s);
        }
        prod = s * W3[c];
    }
    red[threadIdx.x] = prod;
    __syncthreads();
    for (int off = 128; off > 0; off >>= 1){
        if (threadIdx.x < off) red[threadIdx.x] += red[threadIdx.x + off];
        __syncthreads();
    }
    if (threadIdx.x == 0)
        outp[g] = 1.0f / (1.0f + expf(-(red[0] + b3[0])));
}

// ============================ launch ============================

extern "C" void kernel_launch(void* const* d_in, const int* in_sizes, int n_in,
                              void* d_out, int out_size, void* d_ws, size_t ws_size,
                              hipStream_t stream)
{
    const float* x    = (const float*)d_in[0];
    const int*   ei   = (const int*)d_in[1];
    const int*   batch= (const int*)d_in[2];
    const float* Wl[5]; const float* bl[5]; const float* Wr[5];
    for (int i = 0; i < 5; ++i){
        Wl[i] = (const float*)d_in[3 + 3*i];
        bl[i] = (const float*)d_in[4 + 3*i];
        Wr[i] = (const float*)d_in[5 + 3*i];
    }
    const float* pw1 = (const float*)d_in[18]; const float* pb1 = (const float*)d_in[19];
    const float* pw2 = (const float*)d_in[20]; const float* pb2 = (const float*)d_in[21];
    const float* pw3 = (const float*)d_in[22]; const float* pb3 = (const float*)d_in[23];
    float* out = (float*)d_out;

    const int N  = in_sizes[2];
    const int E  = in_sizes[1] / 2;
    const int NG = out_size;
    const int* esrc = ei;
    const int* edst = ei + E;
    const int nbuck = (N + 63) >> BSHIFT;          // 1563
    const int nblk  = (E + EPB - 1) / EPB;         // 782

    // ---- workspace carve ----
    char* p = (char*)d_ws;
    auto carve = [&](size_t bytes)->void* {
        void* r = (void*)p;
        p += (bytes + 255) & ~(size_t)255;
        return r;
    };
    int*   deg     = (int*)  carve((size_t)N * 4);
    int*   row_ptr = (int*)  carve(((size_t)N + 1) * 4);
    int*   csum    = (int*)  carve(4096);
    int*   hist    = (int*)  carve((size_t)nblk * nbuck * 4);
    int*   Tb      = (int*)  carve((size_t)nbuck * 4);
    int*   tbase   = (int*)  carve(((size_t)nbuck + 1) * 4);
    float* invdeg  = (float*)carve((size_t)N * 4);
    int*   gstart  = (int*)  carve(((size_t)NG + 1) * 4);
    int*   srcs    = (int*)  carve((size_t)E * 4);
    unsigned* pairs = (unsigned*)carve((size_t)E * 4);
    unsigned short* xp    = (unsigned short*)carve((size_t)N * 16 * 2);
    unsigned char*  xa    = (unsigned char*) carve((size_t)N * 32);
    unsigned char*  agg8  = (unsigned char*) carve((size_t)N * ROWP);
    unsigned char*  h8A   = (unsigned char*) carve((size_t)N * ROWP);
    unsigned char*  h8B   = (unsigned char*) carve((size_t)N * ROWP);
    unsigned char*  wpack = (unsigned char*) carve((size_t)8 * PACK_BYTES);
    unsigned char*  w1pack= (unsigned char*) carve((size_t)PACK1_BYTES);
    float* biasp   = (float*)carve((size_t)5 * ROWP * 4);
    float* gsum    = (float*)carve((size_t)NG * 1000 * 4);
    float* t1      = (float*)carve((size_t)NG * 500 * 4);

    // ---- zero what must be zero ----
    hipMemsetAsync(gsum, 0, (size_t)NG * 1000 * 4, stream);

    // ---- packing ----
    int xblk = (N * 16 + 255) / 256;
    k_pack_w<<<dim3(NT, KS, 8), 64, 0, stream>>>(
        Wl[1], Wr[1], Wl[2], Wr[2], Wl[3], Wr[3], Wl[4], Wr[4], wpack);
    k_pack_misc<<<xblk + NT + 5, 256, 0, stream>>>(
        x, xp, xa, Wl[0], Wr[0], w1pack,
        bl[0], bl[1], bl[2], bl[3], bl[4], biasp, N, xblk);

    // ---- binned CSR build (no hot global atomics) ----
    k_bin_hist<<<nblk, 256, 0, stream>>>(edst, hist, E, nbuck);
    k_col_scan<<<(nbuck + 63) / 64, 256, 0, stream>>>(hist, Tb, nblk, nbuck);
    k_scan_t<<<1, 256, 0, stream>>>(Tb, tbase, nbuck);
    k_bin_scatter<<<nblk, 256, 0, stream>>>(esrc, edst, hist, tbase, pairs, E, nbuck);
    k_bucket_deg<<<nbuck, 256, 0, stream>>>(pairs, tbase, deg, invdeg, N);
    int nchunks = (N + 1023) / 1024;
    k_scan_sums<<<nchunks, 256, 0, stream>>>(deg, csum, N);
    k_scan_apply<<<nchunks, 256, 0, stream>>>(deg, csum, row_ptr, N, E, nchunks);
    k_place<<<nbuck, 256, 0, stream>>>(pairs, tbase, row_ptr, srcs, N);

    // ---- graph starts (binary search over sorted batch) ----
    k_gstart_bs<<<(NG + 256) / 256, 256, 0, stream>>>(batch, gstart, N, NG);

    // ---- layer 1 (fp8 MFMA over K=32 = [agg11 | x11]) ----
    int gb = (N + 63) / 64;
    k_agg11<<<(N + 7) / 8, 256, 0, stream>>>(xp, row_ptr, srcs, invdeg, xa, N);
    k_layer1_mfma<<<gb, 256, 0, stream>>>(xa, w1pack, biasp, h8A, N);
    k_pool<<<dim3(NG, 8), 256, 0, stream>>>(h8A, gstart, gsum, 0);

    // ---- layers 2..5 (fp8 gather + fp8 MFMA) ----
    unsigned char* hc = h8A; unsigned char* hn = h8B;
    int ab = (N + 3) / 4;
    for (int L = 1; L < 5; ++L){
        k_agg200<<<ab, 256, 0, stream>>>(hc, row_ptr, srcs, invdeg, agg8, N);
        const unsigned char* Wlp = wpack + (size_t)((L-1)*2 + 0) * PACK_BYTES;
        const unsigned char* Wrp = wpack + (size_t)((L-1)*2 + 1) * PACK_BYTES;
        k_sage_mfma<<<gb, 256, 0, stream>>>(agg8, hc, Wlp, Wrp,
                                            biasp + L * ROWP, hn, N);
        k_pool<<<dim3(NG, 8), 256, 0, stream>>>(hn, gstart, gsum, 200 * L);
        unsigned char* t = hc; hc = hn; hn = t;
    }

    // ---- MLP head (pool finalize fused into first layer) ----
    k_mlp_first<<<NG, 256, 0, stream>>>(gsum, gstart, pw1, pb1, t1);
    k_mlp23<<<NG, 256, 0, stream>>>(t1, pw2, pb2, pw3, pb3, out);
}